// Round 4
// baseline (288.076 us; speedup 1.0000x reference)
//
#include <hip/hip_runtime.h>
#include <math.h>

// Problem constants
#define BB 2
#define DD 128
#define LL 2048
#define HH 8
#define OC 1024     // H*D
#define RR_ 128
#define BL (BB*LL)          // 4096
#define NROW (BL*HH)        // 32768
#define XROWS 2052

// Numerics ledger (absmax bf16-quantized; threshold 180.48):
//   r3 full fp64 -> 128 PASS | r2 seq fp32 -> 192 FAIL | r5 tanhf -> FAIL
//   r6 chunk4/8+fp64 tanh -> 128 PASS | r7-r11 MFMA ladder -> 64 PASS
//   r14 fixed C -> 64 PASS, 268us | r15 conv 4x o-tile -> 433us REGRESS (spill)
//   r16 revert -> 267us | r17 B-dbuf -> 267us | r18 repart+dbuf -> FAIL
//   r19 repart no-dbuf -> conv 80->108us REGRESS (latency-bound at 2 w/SIMD;
//   per-wave load chain doubled at fixed occupancy).
//   r20 launch_bounds(256,3): VGPR 112->80 but 80+96AGPR=176>168 -> occupancy
//   request FAILED (still 2 w/SIMD); conv 80->72.8us from pressure relief only.
// r21: conv 8 waves x (32l x 16o), 512-thread block, same 64x64 block tile.
//      Per-wave AGPR 96->48 (accm[2][4]+corr[2][2]); arch ~64 -> unified
//      <=128 -> 4 waves/SIMD (2x latency hiding, the diagnosed deficit).
//      Per-output MFMA chain identical to r16 -> bit-identical, absmax 64.
//      Cost: B-frags fetched 2x/block (L2-resident wenc, cheap).

typedef __bf16  bf16x8  __attribute__((ext_vector_type(8)));
typedef float   float4v __attribute__((ext_vector_type(4)));

__device__ __forceinline__ void enc2(const float* src, bf16x8& p1, bf16x8& p2) {
    #pragma unroll
    for (int j = 0; j < 8; ++j) {
        float v = src[j];
        __bf16 h1 = (__bf16)v;
        p1[j] = h1;
        p2[j] = (__bf16)(v - (float)h1);
    }
}

// phi = SR*tanh(u1*u2/SR) = SR*(1 - 2/(2^y + 1)), y = u1*u2*(2/sqrt(128))*log2e.
__device__ __forceinline__ float fast_phi(double u1, double u2) {
    const double TWO_ISR = 0.17677669529663688110;  // 2/sqrt(128) = sqrt(2)/8
    const double LOG2E   = 1.44269504088896340736;  // log2(e)
    const double SR      = 11.313708498984760390;   // sqrt(128)
    double y = (u1*u2) * (TWO_ISR * LOG2E);
    y = fmin(fmax(y, -1020.4), 1020.4);
    double n = rint(y);
    double f = y - n;
    float ff = (float)f;
    float q;
    q = fmaf(1.01780860092396960e-7f, ff, 1.32154867901443094e-6f);
    q = fmaf(q, ff, 1.52527338040598403e-5f);
    q = fmaf(q, ff, 1.54035303933816099e-4f);
    q = fmaf(q, ff, 1.33335581464284434e-3f);
    q = fmaf(q, ff, 9.61812910762847716e-3f);
    q = fmaf(q, ff, 5.55041086648215800e-2f);
    double t2   = fma(f, (double)q, 0.24022650695910071233);
    double head = fma(f, 0.69314718055994530942, 1.0);
    double E0   = fma(f*f, t2, head);
    int ni = (int)n;
    double En = __hiloint2double((ni + 1023) << 20, 0);   // 2^n
    double E  = E0 * En;
    double den = E + 1.0;
    double r = (double)__builtin_amdgcn_rcpf((float)den);
    r = r * fma(-den, r, 2.0);
    r = r * fma(-den, r, 2.0);
    double t = fma(-2.0, r, 1.0);
    return (float)(SR * t);
}

// ---------------------------------------------------------------------------
// Kernel 0: fused encode (weights + x). (r11-proven)
// ---------------------------------------------------------------------------
__global__ __launch_bounds__(256) void enc_fused_k(
    const float* __restrict__ q_w, const float* __restrict__ k_w,
    const float* __restrict__ v_w, const float* __restrict__ pw,
    const float* __restrict__ g1_q, const float* __restrict__ g2_q,
    const float* __restrict__ g1_k, const float* __restrict__ g2_k,
    const float* __restrict__ x,
    __bf16* __restrict__ wenc, __bf16* __restrict__ genc,
    __bf16* __restrict__ venc, __bf16* __restrict__ penc,
    __bf16* __restrict__ xenc)
{
    __shared__ float t[32][33];
    const int bid = blockIdx.x;
    const int tid = threadIdx.x;
    if (bid < 2304) {
        const int gid = bid*256 + tid;
        if (gid < 262144) {
            const int o = gid >> 7, c = gid & 127;
            #pragma unroll
            for (int tt = 0; tt < 3; ++tt) {
                float v = (o < 1024) ? q_w[(o*128 + c)*3 + tt]
                                     : k_w[((o-1024)*128 + c)*3 + tt];
                __bf16 h1 = (__bf16)v;  float r1 = v - (float)h1;
                __bf16 h2 = (__bf16)r1; float r2 = r1 - (float)h2;
                __bf16 h3 = (__bf16)r2;
                wenc[((size_t)(0*3 + tt)*2048 + o)*128 + c] = h1;
                wenc[((size_t)(1*3 + tt)*2048 + o)*128 + c] = h2;
                wenc[((size_t)(2*3 + tt)*2048 + o)*128 + c] = h3;
            }
        } else if (gid < 262144 + 65536) {
            const int g = gid - 262144;
            const int mat = g >> 14, rem = g & 16383;
            const int r = rem >> 7, d = rem & 127;
            const float* src = (mat == 0) ? g1_q : (mat == 1) ? g2_q
                             : (mat == 2) ? g1_k : g2_k;
            float v = src[d*RR_ + r];
            __bf16 h1 = (__bf16)v;  float r1 = v - (float)h1;
            __bf16 h2 = (__bf16)r1; float r2 = r1 - (float)h2;
            __bf16 h3 = (__bf16)r2;
            genc[((size_t)(mat*3 + 0)*128 + r)*128 + d] = h1;
            genc[((size_t)(mat*3 + 1)*128 + r)*128 + d] = h2;
            genc[((size_t)(mat*3 + 2)*128 + r)*128 + d] = h3;
        } else if (gid < 262144 + 65536 + 131072) {
            const int g = gid - 262144 - 65536;
            const int o = g >> 7, c = g & 127;
            float v = v_w[o*128 + c];
            __bf16 h1 = (__bf16)v;  float r1 = v - (float)h1;
            __bf16 h2 = (__bf16)r1;
            venc[((size_t)0*1024 + o)*128 + c] = h1;
            venc[((size_t)1*1024 + o)*128 + c] = h2;
        } else if (gid < 262144 + 65536 + 131072 + 131072) {
            const int g = gid - 262144 - 65536 - 131072;
            const int j = g >> 10, k = g & 1023;
            float v = pw[(size_t)j*OC + k];
            __bf16 h1 = (__bf16)v;  float r1 = v - (float)h1;
            __bf16 h2 = (__bf16)r1;
            penc[((size_t)(0*128 + j))*OC + k] = h1;
            penc[((size_t)(1*128 + j))*OC + k] = h2;
        }
    } else {
        const int g = bid - 2304;
        const int lt = g & 63, ct = (g >> 6) & 3, b = g >> 8;
        const int l0 = lt*32, c0 = ct*32;
        for (int e = tid; e < 32*32; e += 256) {
            int c = e >> 5, l = e & 31;
            t[c][l] = x[((size_t)(b*DD + c0 + c))*LL + l0 + l];
        }
        __syncthreads();
        for (int e = tid; e < 32*32; e += 256) {
            int l = e >> 5, c = e & 31;
            float v = t[c][l];
            __bf16 h1 = (__bf16)v;  float r1 = v - (float)h1;
            __bf16 h2 = (__bf16)r1; float r2 = r1 - (float)h2;
            __bf16 h3 = (__bf16)r2;
            const size_t row = (size_t)(l0 + l + 2);
            xenc[((size_t)(0*2 + b)*XROWS + row)*128 + c0 + c] = h1;
            xenc[((size_t)(1*2 + b)*XROWS + row)*128 + c0 + c] = h2;
            xenc[((size_t)(2*2 + b)*XROWS + row)*128 + c0 + c] = h3;
        }
        if (lt == 0 && ct == 0) {
            for (int e = tid; e < 2*128; e += 256) {
                int row = e >> 7, c = e & 127;
                xenc[((size_t)(0*2 + b)*XROWS + row)*128 + c] = (__bf16)0.f;
                xenc[((size_t)(1*2 + b)*XROWS + row)*128 + c] = (__bf16)0.f;
                xenc[((size_t)(2*2 + b)*XROWS + row)*128 + c] = (__bf16)0.f;
            }
        }
    }
}

// ---------------------------------------------------------------------------
// Kernel 1: fused q+k conv (3-plane/6-pass) AND v (2-plane/4-pass).
// r21: 512 threads = 8 waves; wave (wlh = wave>>2) owns l-half, (wo = wave&3)
// owns one 16-o subtile. Per-wave AGPR 48 (accm[2][4]+corr[2][2]) ->
// unified regs ~112-128 -> 4 waves/SIMD. Per-output MFMA chain identical
// to r16 (same operands, same idx order) -> bit-identical arithmetic.
// grid (64, 48): y<32 -> q|k conv o-tile, y>=32 -> v o-tile.
// ---------------------------------------------------------------------------
__global__ __launch_bounds__(512, 4) void conv_mfma_k(
    const __bf16* __restrict__ xenc, const __bf16* __restrict__ wenc,
    const __bf16* __restrict__ venc,
    const float* __restrict__ q_b, const float* __restrict__ k_b,
    const float* __restrict__ gamma_q, const float* __restrict__ beta_q,
    const float* __restrict__ gamma_k, const float* __restrict__ beta_k,
    float* __restrict__ q_s, float* __restrict__ k_s, float* __restrict__ v_s)
{
    __shared__ __bf16 As[3][66][136];
    const int tid  = threadIdx.x;
    const int wave = tid >> 6;
    const int lane = tid & 63;
    const int m    = lane & 15;
    const int quad = lane >> 4;
    const int bx = blockIdx.x;
    const int b  = bx >> 5;
    const int lb0 = (bx & 31) << 6;
    const int yt = blockIdx.y;
    const int wlh = wave >> 2;     // l-half (0/1) of the 64-row tile
    const int wo  = wave & 3;      // o-subtile (0..3) of the 64-col o tile

    for (int e = tid; e < 3*66*16; e += 512) {
        const int p = e / (66*16), rem = e % (66*16);
        const int row = rem >> 4, cg = rem & 15;
        *(bf16x8*)&As[p][row][cg*8] =
            *(const bf16x8*)&xenc[((size_t)(p*2 + b)*XROWS + lb0 + row)*128 + cg*8];
    }
    __syncthreads();

    if (yt < 32) {
        const int o0 = yt << 6;
        const int osub = o0 + wo*16;
        float4v accm[2][4];
        float4v corr[2][2];
        #pragma unroll
        for (int lt = 0; lt < 2; ++lt) {
            corr[lt][0] = (float4v){0.f,0.f,0.f,0.f};
            corr[lt][1] = (float4v){0.f,0.f,0.f,0.f};
            #pragma unroll
            for (int c = 0; c < 4; ++c) accm[lt][c] = (float4v){0.f,0.f,0.f,0.f};
        }
        #pragma unroll
        for (int idx = 0; idx < 12; ++idx) {
            const int cidx = idx / 3, t = idx % 3;
            const int c0 = cidx << 5;
            size_t base = ((size_t)t*2048 + osub + m)*128 + c0 + quad*8;
            bf16x8 B1 = *(const bf16x8*)&wenc[base];
            bf16x8 B2 = *(const bf16x8*)&wenc[base + (size_t)3*2048*128];
            bf16x8 B3 = *(const bf16x8*)&wenc[base + (size_t)6*2048*128];
            #pragma unroll
            for (int lt = 0; lt < 2; ++lt) {
                const int row = wlh*32 + lt*16 + m + t;
                bf16x8 A1 = *(const bf16x8*)&As[0][row][c0 + quad*8];
                bf16x8 A2 = *(const bf16x8*)&As[1][row][c0 + quad*8];
                bf16x8 A3 = *(const bf16x8*)&As[2][row][c0 + quad*8];
                accm[lt][cidx] = __builtin_amdgcn_mfma_f32_16x16x32_bf16(A1, B1, accm[lt][cidx], 0, 0, 0);
                corr[lt][0] = __builtin_amdgcn_mfma_f32_16x16x32_bf16(A1, B2, corr[lt][0], 0, 0, 0);
                corr[lt][1] = __builtin_amdgcn_mfma_f32_16x16x32_bf16(A2, B1, corr[lt][1], 0, 0, 0);
                corr[lt][0] = __builtin_amdgcn_mfma_f32_16x16x32_bf16(A1, B3, corr[lt][0], 0, 0, 0);
                corr[lt][1] = __builtin_amdgcn_mfma_f32_16x16x32_bf16(A3, B1, corr[lt][1], 0, 0, 0);
                corr[lt][0] = __builtin_amdgcn_mfma_f32_16x16x32_bf16(A2, B2, corr[lt][0], 0, 0, 0);
            }
        }
        const int is_k = (o0 >= 1024);
        const double g  = (double)(is_k ? gamma_k[0] : gamma_q[0]);
        const double be = (double)(is_k ? beta_k[0]  : beta_q[0]);
        const int o_global = osub + m;
        const int o_local  = o_global - (is_k ? 1024 : 0);
        const double bias  = (double)(is_k ? k_b[o_local] : q_b[o_local]);
        float* dest = is_k ? k_s : q_s;
        #pragma unroll
        for (int lt = 0; lt < 2; ++lt) {
            #pragma unroll
            for (int reg = 0; reg < 4; ++reg) {
                double s = (double)corr[lt][0][reg] + (double)corr[lt][1][reg];
                #pragma unroll
                for (int c = 0; c < 4; ++c) s += (double)accm[lt][c][reg];
                const int l = lb0 + wlh*32 + lt*16 + quad*4 + reg;
                dest[((size_t)(b*LL + l))*OC + o_local] = (float)(g*(s + bias) + be);
            }
        }
    } else {
        const int o0 = (yt - 32) << 6;
        const int osub = o0 + wo*16;
        float4v accm[2][4];
        float4v corr[2];
        #pragma unroll
        for (int lt = 0; lt < 2; ++lt) {
            corr[lt] = (float4v){0.f,0.f,0.f,0.f};
            #pragma unroll
            for (int c = 0; c < 4; ++c) accm[lt][c] = (float4v){0.f,0.f,0.f,0.f};
        }
        #pragma unroll
        for (int cidx = 0; cidx < 4; ++cidx) {
            const int c0 = cidx << 5;
            size_t base = ((size_t)(osub + m))*128 + c0 + quad*8;
            bf16x8 B1 = *(const bf16x8*)&venc[base];
            bf16x8 B2 = *(const bf16x8*)&venc[base + (size_t)1024*128];
            #pragma unroll
            for (int lt = 0; lt < 2; ++lt) {
                const int row = wlh*32 + lt*16 + m + 2;
                bf16x8 A1 = *(const bf16x8*)&As[0][row][c0 + quad*8];
                bf16x8 A2 = *(const bf16x8*)&As[1][row][c0 + quad*8];
                accm[lt][cidx] = __builtin_amdgcn_mfma_f32_16x16x32_bf16(A1, B1, accm[lt][cidx], 0, 0, 0);
                corr[lt] = __builtin_amdgcn_mfma_f32_16x16x32_bf16(A1, B2, corr[lt], 0, 0, 0);
                corr[lt] = __builtin_amdgcn_mfma_f32_16x16x32_bf16(A2, B1, corr[lt], 0, 0, 0);
                corr[lt] = __builtin_amdgcn_mfma_f32_16x16x32_bf16(A2, B2, corr[lt], 0, 0, 0);
            }
        }
        const int o_local = osub + m;
        #pragma unroll
        for (int lt = 0; lt < 2; ++lt) {
            #pragma unroll
            for (int reg = 0; reg < 4; ++reg) {
                float s = corr[lt][reg];
                #pragma unroll
                for (int c = 0; c < 4; ++c) s += accm[lt][c][reg];
                const int l = lb0 + wlh*32 + lt*16 + quad*4 + reg;
                v_s[((size_t)(b*LL + l))*OC + o_local] = s;
            }
        }
    }
}

// ---------------------------------------------------------------------------
// Kernel 2: sketch q+k fused, 3-plane/6-pass MFMA in-place; fast_phi epilogue.
// ---------------------------------------------------------------------------
__global__ __launch_bounds__(256) void sketch_mfma_k(
    float* __restrict__ q_s, float* __restrict__ k_s,
    const __bf16* __restrict__ genc_all)
{
    __shared__ __bf16 As[3][32][136];
    const int tid  = threadIdx.x;
    const int wave = tid >> 6;
    const int lane = tid & 63;
    const int m    = lane & 15;
    const int quad = lane >> 4;
    const int half = blockIdx.x >> 10;
    float* buf = half ? k_s : q_s;
    const __bf16* genc = genc_all + (size_t)half*2*3*128*128;
    const size_t i0 = (size_t)(blockIdx.x & 1023) * 32;

    for (int e = tid; e < 32*128; e += 256) {
        int row = e >> 7, d = e & 127;
        float v = buf[(i0 + row)*RR_ + d];
        __bf16 h1 = (__bf16)v;  float r1 = v - (float)h1;
        __bf16 h2 = (__bf16)r1; float r2 = r1 - (float)h2;
        __bf16 h3 = (__bf16)r2;
        As[0][row][d] = h1; As[1][row][d] = h2; As[2][row][d] = h3;
    }
    __syncthreads();

    float4v accm[2][2][2], corr[2][2][2];
    #pragma unroll
    for (int mt = 0; mt < 2; ++mt)
        #pragma unroll
        for (int nt = 0; nt < 2; ++nt)
            #pragma unroll
            for (int mat = 0; mat < 2; ++mat) {
                accm[mt][nt][mat] = (float4v){0.f,0.f,0.f,0.f};
                corr[mt][nt][mat] = (float4v){0.f,0.f,0.f,0.f};
            }

    #pragma unroll
    for (int ck = 0; ck < 4; ++ck) {
        const int k0 = ck << 5;
        bf16x8 A1[2], A2[2], A3[2];
        #pragma unroll
        for (int mt = 0; mt < 2; ++mt) {
            A1[mt] = *(const bf16x8*)&As[0][mt*16 + m][k0 + quad*8];
            A2[mt] = *(const bf16x8*)&As[1][mt*16 + m][k0 + quad*8];
            A3[mt] = *(const bf16x8*)&As[2][mt*16 + m][k0 + quad*8];
        }
        #pragma unroll
        for (int nt = 0; nt < 2; ++nt) {
            const int r = wave*32 + nt*16 + m;
            #pragma unroll
            for (int mat = 0; mat < 2; ++mat) {
                size_t base = ((size_t)(mat*3)*128 + r)*128 + k0 + quad*8;
                bf16x8 B1 = *(const bf16x8*)&genc[base];
                bf16x8 B2 = *(const bf16x8*)&genc[base + (size_t)128*128];
                bf16x8 B3 = *(const bf16x8*)&genc[base + (size_t)2*128*128];
                #pragma unroll
                for (int mt = 0; mt < 2; ++mt) {
                    accm[mt][nt][mat] = __builtin_amdgcn_mfma_f32_16x16x32_bf16(A1[mt], B1, accm[mt][nt][mat], 0, 0, 0);
                    corr[mt][nt][mat] = __builtin_amdgcn_mfma_f32_16x16x32_bf16(A1[mt], B2, corr[mt][nt][mat], 0, 0, 0);
                    corr[mt][nt][mat] = __builtin_amdgcn_mfma_f32_16x16x32_bf16(A2[mt], B1, corr[mt][nt][mat], 0, 0, 0);
                    corr[mt][nt][mat] = __builtin_amdgcn_mfma_f32_16x16x32_bf16(A1[mt], B3, corr[mt][nt][mat], 0, 0, 0);
                    corr[mt][nt][mat] = __builtin_amdgcn_mfma_f32_16x16x32_bf16(A3[mt], B1, corr[mt][nt][mat], 0, 0, 0);
                    corr[mt][nt][mat] = __builtin_amdgcn_mfma_f32_16x16x32_bf16(A2[mt], B2, corr[mt][nt][mat], 0, 0, 0);
                }
            }
        }
    }
    __syncthreads();

    #pragma unroll
    for (int mt = 0; mt < 2; ++mt)
        #pragma unroll
        for (int nt = 0; nt < 2; ++nt)
            #pragma unroll
            for (int reg = 0; reg < 4; ++reg) {
                double u1 = (double)accm[mt][nt][0][reg] + (double)corr[mt][nt][0][reg];
                double u2 = (double)accm[mt][nt][1][reg] + (double)corr[mt][nt][1][reg];
                const size_t row = i0 + mt*16 + quad*4 + reg;
                const int col = wave*32 + nt*16 + m;
                buf[row*RR_ + col] = fast_phi(u1, u2);
            }
}

// ---------------------------------------------------------------------------
// Kernel 3: KV^T partials via 2-plane MFMA + fp64 Ksum partials (r10-proven).
// ---------------------------------------------------------------------------
__global__ __launch_bounds__(512) void kv_mfma_k(
    const float* __restrict__ phi_k, const float* __restrict__ v,
    float* __restrict__ part_kv, double* __restrict__ part_ks)
{
    __shared__ float Pt[128*36];
    __shared__ float Vt[128*36];
    __shared__ double ksred[512];
    const int tid  = threadIdx.x;
    const int wave = tid >> 6;
    const int lane = tid & 63;
    const int m    = lane & 15;
    const int quad = lane >> 4;
    const int split = blockIdx.x;
    const int bh    = blockIdx.y;
    const int b = bh >> 3, h = bh & 7;
    const int lbase = split * 128;
    const int dh = wave & 1;
    const int rq = wave >> 1;

    float4v accm[4][2], corr[4][2];
    #pragma unroll
    for (int mt = 0; mt < 4; ++mt)
        #pragma unroll
        for (int nt = 0; nt < 2; ++nt) {
            accm[mt][nt] = (float4v){0.f,0.f,0.f,0.f};
            corr[mt][nt] = (float4v){0.f,0.f,0.f,0.f};
        }
    double ks = 0.0;

    for (int ch = 0; ch < 4; ++ch) {
        __syncthreads();
        for (int e = tid; e < 32*128; e += 512) {
            const int l = e >> 7, r = e & 127;
            size_t base = ((size_t)(b*LL + lbase + ch*32 + l)*HH + h)*RR_;
            float pv = phi_k[base + r];
            float vv = v[base + r];
            Pt[r*36 + l] = pv;
            Vt[r*36 + l] = vv;
            ks += (double)pv;
        }
        __syncthreads();
        bf16x8 A1[4], A2[4], B1[2], B2[2];
        #pragma unroll
        for (int mt = 0; mt < 4; ++mt)
            enc2(&Vt[(dh*64 + mt*16 + m)*36 + quad*8], A1[mt], A2[mt]);
        #pragma unroll
        for (int nt = 0; nt < 2; ++nt)
            enc2(&Pt[(rq*32 + nt*16 + m)*36 + quad*8], B1[nt], B2[nt]);
        #pragma unroll
        for (int mt = 0; mt < 4; ++mt)
            #pragma unroll
            for (int nt = 0; nt < 2; ++nt) {
                accm[mt][nt] = __builtin_amdgcn_mfma_f32_16x16x32_bf16(A1[mt], B1[nt], accm[mt][nt], 0, 0, 0);
                corr[mt][nt] = __builtin_amdgcn_mfma_f32_16x16x32_bf16(A1[mt], B2[nt], corr[mt][nt], 0, 0, 0);
                corr[mt][nt] = __builtin_amdgcn_mfma_f32_16x16x32_bf16(A2[mt], B1[nt], corr[mt][nt], 0, 0, 0);
                corr[mt][nt] = __builtin_amdgcn_mfma_f32_16x16x32_bf16(A2[mt], B2[nt], corr[mt][nt], 0, 0, 0);
            }
    }

    ksred[tid] = ks;
    __syncthreads();
    if (tid < 128) {
        double s = ksred[tid] + ksred[tid+128] + ksred[tid+256] + ksred[tid+384];
        part_ks[(bh*16 + split)*RR_ + tid] = s;
    }

    float* outp = part_kv + ((size_t)(bh*16 + split))*RR_*DD;
    #pragma unroll
    for (int mt = 0; mt < 4; ++mt)
        #pragma unroll
        for (int nt = 0; nt < 2; ++nt)
            #pragma unroll
            for (int reg = 0; reg < 4; ++reg) {
                const int d = dh*64 + mt*16 + quad*4 + reg;
                const int r = rq*32 + nt*16 + m;
                outp[d*128 + r] = accm[mt][nt][reg] + corr[mt][nt][reg];
            }
}

// ---------------------------------------------------------------------------
// Kernel 4: reduce KVT partials -> bf16 2-plane KVTenc.
// ---------------------------------------------------------------------------
__global__ __launch_bounds__(256) void kvreduce_k(
    const float* __restrict__ part_kv, __bf16* __restrict__ kvt_enc)
{
    const int gid = blockIdx.x*256 + threadIdx.x;
    if (gid >= 16*RR_*DD) return;
    const int bh = gid >> 14;
    const int rd = gid & 16383;
    float s = 0.f;
    #pragma unroll
    for (int c = 0; c < 16; ++c)
        s += part_kv[(((size_t)(bh*16 + c)) << 14) + rd];
    __bf16 h1 = (__bf16)s;
    __bf16 h2 = (__bf16)(s - (float)h1);
    kvt_enc[(size_t)bh*16384 + rd] = h1;
    kvt_enc[(size_t)(16 + bh)*16384 + rd] = h2;
}

// ---------------------------------------------------------------------------
// Kernel 5: numerator MFMA + fp64 den (r10-proven).
// ---------------------------------------------------------------------------
__global__ __launch_bounds__(256) void numden_mfma_k(
    const float* __restrict__ phi_q, const __bf16* __restrict__ kvt_enc,
    const double* __restrict__ part_ks, float* __restrict__ o_out)
{
    __shared__ float Pq[64*132];
    __shared__ double Ks_s[128];
    __shared__ double den_s[64];
    const int tid  = threadIdx.x;
    const int wave = tid >> 6;
    const int lane = tid & 63;
    const int m    = lane & 15;
    const int quad = lane >> 4;
    const int lt = blockIdx.x;
    const int bh = blockIdx.y;
    const int b = bh >> 3, h = bh & 7;
    const int l0 = lt * 64;

    if (tid < 128) {
        double s = 0.0;
        #pragma unroll
        for (int c = 0; c < 16; ++c) s += part_ks[(bh*16 + c)*RR_ + tid];
        Ks_s[tid] = s;
    }
    for (int e = tid; e < 64*128; e += 256) {
        const int l = e >> 7, r = e & 127;
        Pq[l*132 + r] = phi_q[((size_t)(b*LL + l0 + l)*HH + h)*RR_ + r];
    }
    __syncthreads();

    double den = 0.0;
    if (tid < 64) {
        #pragma unroll
        for (int r = 0; r < 128; ++r)
            den += (double)Pq[tid*132 + r] * Ks_s[r];
    }

    float4v accm[4][2], corr[4][2];
    #pragma unroll
    for (int mt = 0; mt < 4; ++mt)
        #pragma unroll
        for (int nt = 0; nt < 2; ++nt) {
            accm[mt][nt] = (float4v){0.f,0.f,0.f,0.f};
            corr[mt][nt] = (float4v){0.f,0.f,0.f,0.f};
        }

    #pragma unroll
    for (int ck = 0; ck < 4; ++ck) {
        const int k0 = ck << 5;
        bf16x8 A1[4], A2[4];
        #pragma unroll
        for (int mt = 0; mt < 4; ++mt)
            enc2(&Pq[(mt*16 + m)*132 + k0 + quad*8], A1[mt], A2[mt]);
        #pragma unroll
        for (int nt = 0; nt < 2; ++nt) {
            const int d = wave*32 + nt*16 + m;
            size_t base = ((size_t)bh*128 + d)*128 + k0 + quad*8;
            bf16x8 B1 = *(const bf16x8*)&kvt_enc[base];
            bf16x8 B2 = *(const bf16x8*)&kvt_enc[base + (size_t)16*16384];
            #pragma unroll
            for (int mt = 0; mt < 4; ++mt) {
                accm[mt][nt] = __builtin_amdgcn_mfma_f32_16x16x32_bf16(A1[mt], B1, accm[mt][nt], 0, 0, 0);
                corr[mt][nt] = __builtin_amdgcn_mfma_f32_16x16x32_bf16(A1[mt], B2, corr[mt][nt], 0, 0, 0);
                corr[mt][nt] = __builtin_amdgcn_mfma_f32_16x16x32_bf16(A2[mt], B1, corr[mt][nt], 0, 0, 0);
                corr[mt][nt] = __builtin_amdgcn_mfma_f32_16x16x32_bf16(A2[mt], B2, corr[mt][nt], 0, 0, 0);
            }
        }
    }

    __syncthreads();
    if (tid < 64) den_s[tid] = den;
    __syncthreads();

    #pragma unroll
    for (int mt = 0; mt < 4; ++mt)
        #pragma unroll
        for (int nt = 0; nt < 2; ++nt)
            #pragma unroll
            for (int reg = 0; reg < 4; ++reg) {
                const int ll = mt*16 + quad*4 + reg;
                const int d  = wave*32 + nt*16 + m;
                const float inv = (float)(1.0 / (den_s[ll] + 1e-6));
                o_out[((size_t)(b*LL + l0 + ll))*OC + h*DD + d] =
                    (accm[mt][nt][reg] + corr[mt][nt][reg]) * inv;
            }
}

// ---------------------------------------------------------------------------
// Kernel 6: output projection partials via 2-plane MFMA (r10-proven).
// ---------------------------------------------------------------------------
__global__ __launch_bounds__(256) void proj_part_mfma_k(
    const float* __restrict__ o_s, const __bf16* __restrict__ penc,
    float* __restrict__ part)
{
    __shared__ float As[32*260];
    const int tid  = threadIdx.x;
    const int wave = tid >> 6;
    const int lane = tid & 63;
    const int m    = lane & 15;
    const int quad = lane >> 4;
    const int row0  = blockIdx.x * 32;
    const int kbase = blockIdx.y * 256;

    for (int e = tid; e < 32*256; e += 256) {
        const int row = e >> 8, k = e & 255;
        As[row*260 + k] = o_s[(size_t)(row0 + row)*OC + kbase + k];
    }
    __syncthreads();

    float4v accm[2][2], corr[2][2];
    #pragma unroll
    for (int mt = 0; mt < 2; ++mt)
        #pragma unroll
        for (int nt = 0; nt < 2; ++nt) {
            accm[mt][nt] = (float4v){0.f,0.f,0.f,0.f};
            corr[mt][nt] = (float4v){0.f,0.f,0.f,0.f};
        }

    #pragma unroll
    for (int ck = 0; ck < 8; ++ck) {
        const int k0 = ck << 5;
        bf16x8 A1[2], A2[2];
        #pragma unroll
        for (int mt = 0; mt < 2; ++mt)
            enc2(&As[(mt*16 + m)*260 + k0 + quad*8], A1[mt], A2[mt]);
        #pragma unroll
        for (int nt = 0; nt < 2; ++nt) {
            const int j = wave*32 + nt*16 + m;
            size_t base = ((size_t)j)*OC + kbase + k0 + quad*8;
            bf16x8 B1 = *(const bf16x8*)&penc[base];
            bf16x8 B2 = *(const bf16x8*)&penc[base + (size_t)128*OC];
            #pragma unroll
            for (int mt = 0; mt < 2; ++mt) {
                accm[mt][nt] = __builtin_amdgcn_mfma_f32_16x16x32_bf16(A1[mt], B1, accm[mt][nt], 0, 0, 0);
                corr[mt][nt] = __builtin_amdgcn_mfma_f32_16x16x32_bf16(A1[mt], B2, corr[mt][nt], 0, 0, 0);
                corr[mt][nt] = __builtin_amdgcn_mfma_f32_16x16x32_bf16(A2[mt], B1, corr[mt][nt], 0, 0, 0);
                corr[mt][nt] = __builtin_amdgcn_mfma_f32_16x16x32_bf16(A2[mt], B2, corr[mt][nt], 0, 0, 0);
            }
        }
    }

    float* outp = part + (size_t)blockIdx.y*BL*DD;
    #pragma unroll
    for (int mt = 0; mt < 2; ++mt)
        #pragma unroll
        for (int nt = 0; nt < 2; ++nt)
            #pragma unroll
            for (int reg = 0; reg < 4; ++reg) {
                const int row = row0 + mt*16 + quad*4 + reg;
                const int j   = wave*32 + nt*16 + m;
                outp[(size_t)row*DD + j] = accm[mt][nt][reg] + corr[mt][nt][reg];
            }
}

// ---------------------------------------------------------------------------
// Kernel 7: reduce the 4 K-split partials + bias.
// ---------------------------------------------------------------------------
__global__ __launch_bounds__(256) void proj_reduce_k(
    const float* __restrict__ part, const float* __restrict__ pb,
    float* __restrict__ out)
{
    const int gid = blockIdx.x*256 + threadIdx.x;
    if (gid >= BL*DD/4) return;
    const float4* p4 = (const float4*)part;
    float4 s = p4[gid];
    #pragma unroll
    for (int c = 1; c < 4; ++c) {
        float4 t = p4[gid + (size_t)c*(BL*DD/4)];
        s.x += t.x; s.y += t.y; s.z += t.z; s.w += t.w;
    }
    const int col = (gid << 2) & (DD-1);
    s.x += pb[col]; s.y += pb[col+1]; s.z += pb[col+2]; s.w += pb[col+3];
    ((float4*)out)[gid] = s;
}

// ---------------------------------------------------------------------------
extern "C" void kernel_launch(void* const* d_in, const int* in_sizes, int n_in,
                              void* d_out, int out_size, void* d_ws, size_t ws_size,
                              hipStream_t stream) {
    const float* x       = (const float*)d_in[0];
    const float* q_w     = (const float*)d_in[1];
    const float* q_b     = (const float*)d_in[2];
    const float* k_w     = (const float*)d_in[3];
    const float* k_b     = (const float*)d_in[4];
    const float* v_w     = (const float*)d_in[5];
    const float* g1_q    = (const float*)d_in[6];
    const float* g2_q    = (const float*)d_in[7];
    const float* g1_k    = (const float*)d_in[8];
    const float* g2_k    = (const float*)d_in[9];
    const float* gamma_q = (const float*)d_in[10];
    const float* beta_q  = (const float*)d_in[11];
    const float* gamma_k = (const float*)d_in[12];
    const float* beta_k  = (const float*)d_in[13];
    const float* proj_w  = (const float*)d_in[14];
    const float* proj_b  = (const float*)d_in[15];

    float* f = (float*)d_ws;
    float* q_s     = f;                        // 4,194,304 floats
    float* k_s     = f + 4194304;              // 4,194,304
    float* v_s     = f + 8388608;              // 4,194,304
    float* part_kv = f + 12582912;             // 4,194,304 (scratch: wenc/xenc/kv parts/proj parts)
    double* part_ks = (double*)(f + 16777216); // 32,768 doubles
    __bf16* kvt_enc = (__bf16*)(f + 16842752); // 524,288 bf16
    __bf16* genc   = (__bf16*)(f + 17104896);  // 196,608 bf16
    __bf16* venc   = (__bf16*)(f + 17203200);  // 262,144 bf16
    __bf16* penc   = (__bf16*)(f + 17334272);  // 262,144 bf16
    float* o_s     = k_s;                      // reuse (phi_k dead after kv_mfma)
    float* proj_part = part_kv;                // reuse (kv parts dead after kvreduce)
    __bf16* wenc   = (__bf16*)(f + 12582912);
    __bf16* xenc   = (__bf16*)(f + 13762560);

    dim3 blk(256);
    enc_fused_k<<<2816, blk, 0, stream>>>(q_w, k_w, v_w, proj_w,
                                          g1_q, g2_q, g1_k, g2_k, x,
                                          wenc, genc, venc, penc, xenc);
    conv_mfma_k<<<dim3(64,48), dim3(512), 0, stream>>>(xenc, wenc, venc, q_b, k_b,
                                                       gamma_q, beta_q, gamma_k, beta_k,
                                                       q_s, k_s, v_s);
    sketch_mfma_k<<<2048, blk, 0, stream>>>(q_s, k_s, genc);
    kv_mfma_k<<<dim3(16,16), dim3(512), 0, stream>>>(k_s, v_s, part_kv, part_ks);
    kvreduce_k<<<1024, blk, 0, stream>>>(part_kv, kvt_enc);
    numden_mfma_k<<<dim3(32,16), blk, 0, stream>>>(q_s, kvt_enc, part_ks, o_s);
    proj_part_mfma_k<<<dim3(128,4), blk, 0, stream>>>(o_s, penc, proj_part);
    proj_reduce_k<<<512, blk, 0, stream>>>(proj_part, proj_b, (float*)d_out);
}

// Round 5
// 265.092 us; speedup vs baseline: 1.0867x; 1.0867x over previous
//
#include <hip/hip_runtime.h>
#include <math.h>

// Problem constants
#define BB 2
#define DD 128
#define LL 2048
#define HH 8
#define OC 1024     // H*D
#define RR_ 128
#define BL (BB*LL)          // 4096
#define NROW (BL*HH)        // 32768
#define XROWS 2052

// Numerics ledger (absmax bf16-quantized; threshold 180.48):
//   r3 full fp64 -> 128 PASS | r2 seq fp32 -> 192 FAIL | r5 tanhf -> FAIL
//   r6 chunk4/8+fp64 tanh -> 128 PASS | r7-r11 MFMA ladder -> 64 PASS
//   r14 fixed C -> 64 PASS, 268us | r15 conv 4x o-tile -> 433us REGRESS (spill)
//   r16 revert -> 267us | r17 B-dbuf -> neutral | r18 repart+dbuf -> FAIL
//   r19 repart 32lx32o -> conv 108us REGRESS | r20 lb(256,3): VGPR 80 but
//   80+96AGPR=176>168, occupancy still 2/SIMD; conv 72.8us (pressure relief).
//   r21 8-wave 32lx16o: occupancy 41% but conv 96us REGRESS -> occupancy is
//   NOT binding; the losers doubled B-traffic / halved per-round MFMA run.
// r22: conv keeps r16/r20 wave structure EXACTLY; accumulator fold:
//      one accm[lt] per chunk, folded to fp64 s64[lt][reg] after each cidx
//      (AGPR 96->48 q/k, 80->32 v; fp64-reassoc-only change, chunk-32 fp32
//      chains bit-identical) + lb(256,3) -> 3 waves/SIMD at same loop shape.
//      LDS 3x54272=162816<=163840. Plus float4 staging in sketch/numden/
//      proj_part (values identical). kv staging untouched (ks is r-keyed).

typedef __bf16  bf16x8  __attribute__((ext_vector_type(8)));
typedef float   float4v __attribute__((ext_vector_type(4)));

__device__ __forceinline__ void enc2(const float* src, bf16x8& p1, bf16x8& p2) {
    #pragma unroll
    for (int j = 0; j < 8; ++j) {
        float v = src[j];
        __bf16 h1 = (__bf16)v;
        p1[j] = h1;
        p2[j] = (__bf16)(v - (float)h1);
    }
}

// phi = SR*tanh(u1*u2/SR) = SR*(1 - 2/(2^y + 1)), y = u1*u2*(2/sqrt(128))*log2e.
__device__ __forceinline__ float fast_phi(double u1, double u2) {
    const double TWO_ISR = 0.17677669529663688110;  // 2/sqrt(128) = sqrt(2)/8
    const double LOG2E   = 1.44269504088896340736;  // log2(e)
    const double SR      = 11.313708498984760390;   // sqrt(128)
    double y = (u1*u2) * (TWO_ISR * LOG2E);
    y = fmin(fmax(y, -1020.4), 1020.4);
    double n = rint(y);
    double f = y - n;
    float ff = (float)f;
    float q;
    q = fmaf(1.01780860092396960e-7f, ff, 1.32154867901443094e-6f);
    q = fmaf(q, ff, 1.52527338040598403e-5f);
    q = fmaf(q, ff, 1.54035303933816099e-4f);
    q = fmaf(q, ff, 1.33335581464284434e-3f);
    q = fmaf(q, ff, 9.61812910762847716e-3f);
    q = fmaf(q, ff, 5.55041086648215800e-2f);
    double t2   = fma(f, (double)q, 0.24022650695910071233);
    double head = fma(f, 0.69314718055994530942, 1.0);
    double E0   = fma(f*f, t2, head);
    int ni = (int)n;
    double En = __hiloint2double((ni + 1023) << 20, 0);   // 2^n
    double E  = E0 * En;
    double den = E + 1.0;
    double r = (double)__builtin_amdgcn_rcpf((float)den);
    r = r * fma(-den, r, 2.0);
    r = r * fma(-den, r, 2.0);
    double t = fma(-2.0, r, 1.0);
    return (float)(SR * t);
}

// ---------------------------------------------------------------------------
// Kernel 0: fused encode (weights + x). (r11-proven)
// ---------------------------------------------------------------------------
__global__ __launch_bounds__(256) void enc_fused_k(
    const float* __restrict__ q_w, const float* __restrict__ k_w,
    const float* __restrict__ v_w, const float* __restrict__ pw,
    const float* __restrict__ g1_q, const float* __restrict__ g2_q,
    const float* __restrict__ g1_k, const float* __restrict__ g2_k,
    const float* __restrict__ x,
    __bf16* __restrict__ wenc, __bf16* __restrict__ genc,
    __bf16* __restrict__ venc, __bf16* __restrict__ penc,
    __bf16* __restrict__ xenc)
{
    __shared__ float t[32][33];
    const int bid = blockIdx.x;
    const int tid = threadIdx.x;
    if (bid < 2304) {
        const int gid = bid*256 + tid;
        if (gid < 262144) {
            const int o = gid >> 7, c = gid & 127;
            #pragma unroll
            for (int tt = 0; tt < 3; ++tt) {
                float v = (o < 1024) ? q_w[(o*128 + c)*3 + tt]
                                     : k_w[((o-1024)*128 + c)*3 + tt];
                __bf16 h1 = (__bf16)v;  float r1 = v - (float)h1;
                __bf16 h2 = (__bf16)r1; float r2 = r1 - (float)h2;
                __bf16 h3 = (__bf16)r2;
                wenc[((size_t)(0*3 + tt)*2048 + o)*128 + c] = h1;
                wenc[((size_t)(1*3 + tt)*2048 + o)*128 + c] = h2;
                wenc[((size_t)(2*3 + tt)*2048 + o)*128 + c] = h3;
            }
        } else if (gid < 262144 + 65536) {
            const int g = gid - 262144;
            const int mat = g >> 14, rem = g & 16383;
            const int r = rem >> 7, d = rem & 127;
            const float* src = (mat == 0) ? g1_q : (mat == 1) ? g2_q
                             : (mat == 2) ? g1_k : g2_k;
            float v = src[d*RR_ + r];
            __bf16 h1 = (__bf16)v;  float r1 = v - (float)h1;
            __bf16 h2 = (__bf16)r1; float r2 = r1 - (float)h2;
            __bf16 h3 = (__bf16)r2;
            genc[((size_t)(mat*3 + 0)*128 + r)*128 + d] = h1;
            genc[((size_t)(mat*3 + 1)*128 + r)*128 + d] = h2;
            genc[((size_t)(mat*3 + 2)*128 + r)*128 + d] = h3;
        } else if (gid < 262144 + 65536 + 131072) {
            const int g = gid - 262144 - 65536;
            const int o = g >> 7, c = g & 127;
            float v = v_w[o*128 + c];
            __bf16 h1 = (__bf16)v;  float r1 = v - (float)h1;
            __bf16 h2 = (__bf16)r1;
            venc[((size_t)0*1024 + o)*128 + c] = h1;
            venc[((size_t)1*1024 + o)*128 + c] = h2;
        } else if (gid < 262144 + 65536 + 131072 + 131072) {
            const int g = gid - 262144 - 65536 - 131072;
            const int j = g >> 10, k = g & 1023;
            float v = pw[(size_t)j*OC + k];
            __bf16 h1 = (__bf16)v;  float r1 = v - (float)h1;
            __bf16 h2 = (__bf16)r1;
            penc[((size_t)(0*128 + j))*OC + k] = h1;
            penc[((size_t)(1*128 + j))*OC + k] = h2;
        }
    } else {
        const int g = bid - 2304;
        const int lt = g & 63, ct = (g >> 6) & 3, b = g >> 8;
        const int l0 = lt*32, c0 = ct*32;
        for (int e = tid; e < 32*32; e += 256) {
            int c = e >> 5, l = e & 31;
            t[c][l] = x[((size_t)(b*DD + c0 + c))*LL + l0 + l];
        }
        __syncthreads();
        for (int e = tid; e < 32*32; e += 256) {
            int l = e >> 5, c = e & 31;
            float v = t[c][l];
            __bf16 h1 = (__bf16)v;  float r1 = v - (float)h1;
            __bf16 h2 = (__bf16)r1; float r2 = r1 - (float)h2;
            __bf16 h3 = (__bf16)r2;
            const size_t row = (size_t)(l0 + l + 2);
            xenc[((size_t)(0*2 + b)*XROWS + row)*128 + c0 + c] = h1;
            xenc[((size_t)(1*2 + b)*XROWS + row)*128 + c0 + c] = h2;
            xenc[((size_t)(2*2 + b)*XROWS + row)*128 + c0 + c] = h3;
        }
        if (lt == 0 && ct == 0) {
            for (int e = tid; e < 2*128; e += 256) {
                int row = e >> 7, c = e & 127;
                xenc[((size_t)(0*2 + b)*XROWS + row)*128 + c] = (__bf16)0.f;
                xenc[((size_t)(1*2 + b)*XROWS + row)*128 + c] = (__bf16)0.f;
                xenc[((size_t)(2*2 + b)*XROWS + row)*128 + c] = (__bf16)0.f;
            }
        }
    }
}

// ---------------------------------------------------------------------------
// Kernel 1: fused q+k conv (3-plane/6-pass) AND v (2-plane/4-pass).
// r22: r16/r20 wave structure (4 waves x 16-o subtile, lt=4, direct B loads,
// cidx-major/tap-inner order) with accumulator fold: single accm[lt] per
// chunk, folded into fp64 s64[lt][reg] after each cidx. AGPR 96->48 (q/k),
// 80->32 (v). Per-chunk fp32 MFMA chains bit-identical to r16; only the
// cross-chunk sum moves from fp64-epilogue to fp64-incremental (reassoc,
// ~2^-52). lb(256,3): 48 AGPR + ~110 arch <= 168 -> 3 waves/SIMD.
// grid (64, 48): y<32 -> q|k conv o-tile, y>=32 -> v o-tile.
// ---------------------------------------------------------------------------
__global__ __launch_bounds__(256, 3) void conv_mfma_k(
    const __bf16* __restrict__ xenc, const __bf16* __restrict__ wenc,
    const __bf16* __restrict__ venc,
    const float* __restrict__ q_b, const float* __restrict__ k_b,
    const float* __restrict__ gamma_q, const float* __restrict__ beta_q,
    const float* __restrict__ gamma_k, const float* __restrict__ beta_k,
    float* __restrict__ q_s, float* __restrict__ k_s, float* __restrict__ v_s)
{
    __shared__ __bf16 As[3][66][136];
    const int tid  = threadIdx.x;
    const int wave = tid >> 6;
    const int lane = tid & 63;
    const int m    = lane & 15;
    const int quad = lane >> 4;
    const int bx = blockIdx.x;
    const int b  = bx >> 5;
    const int lb0 = (bx & 31) << 6;
    const int yt = blockIdx.y;

    for (int e = tid; e < 3*66*16; e += 256) {
        const int p = e / (66*16), rem = e % (66*16);
        const int row = rem >> 4, cg = rem & 15;
        *(bf16x8*)&As[p][row][cg*8] =
            *(const bf16x8*)&xenc[((size_t)(p*2 + b)*XROWS + lb0 + row)*128 + cg*8];
    }
    __syncthreads();

    if (yt < 32) {
        const int o0 = yt << 6;
        const int osub = o0 + wave*16;
        float4v corr[4][2];                 // 32 AGPR (all-round correction)
        float4v accm[4];                    // 16 AGPR (current chunk, main plane)
        double  s64[4][4];                  // fp64 running chunk sums (VGPR)
        #pragma unroll
        for (int lt = 0; lt < 4; ++lt) {
            corr[lt][0] = (float4v){0.f,0.f,0.f,0.f};
            corr[lt][1] = (float4v){0.f,0.f,0.f,0.f};
            #pragma unroll
            for (int reg = 0; reg < 4; ++reg) s64[lt][reg] = 0.0;
        }
        #pragma unroll
        for (int cidx = 0; cidx < 4; ++cidx) {
            const int c0 = cidx << 5;
            #pragma unroll
            for (int lt = 0; lt < 4; ++lt) accm[lt] = (float4v){0.f,0.f,0.f,0.f};
            #pragma unroll
            for (int t = 0; t < 3; ++t) {
                size_t base = ((size_t)t*2048 + osub + m)*128 + c0 + quad*8;
                bf16x8 B1 = *(const bf16x8*)&wenc[base];
                bf16x8 B2 = *(const bf16x8*)&wenc[base + (size_t)3*2048*128];
                bf16x8 B3 = *(const bf16x8*)&wenc[base + (size_t)6*2048*128];
                #pragma unroll
                for (int lt = 0; lt < 4; ++lt) {
                    const int row = lt*16 + m + t;
                    bf16x8 A1 = *(const bf16x8*)&As[0][row][c0 + quad*8];
                    bf16x8 A2 = *(const bf16x8*)&As[1][row][c0 + quad*8];
                    bf16x8 A3 = *(const bf16x8*)&As[2][row][c0 + quad*8];
                    accm[lt]    = __builtin_amdgcn_mfma_f32_16x16x32_bf16(A1, B1, accm[lt], 0, 0, 0);
                    corr[lt][0] = __builtin_amdgcn_mfma_f32_16x16x32_bf16(A1, B2, corr[lt][0], 0, 0, 0);
                    corr[lt][1] = __builtin_amdgcn_mfma_f32_16x16x32_bf16(A2, B1, corr[lt][1], 0, 0, 0);
                    corr[lt][0] = __builtin_amdgcn_mfma_f32_16x16x32_bf16(A1, B3, corr[lt][0], 0, 0, 0);
                    corr[lt][1] = __builtin_amdgcn_mfma_f32_16x16x32_bf16(A3, B1, corr[lt][1], 0, 0, 0);
                    corr[lt][0] = __builtin_amdgcn_mfma_f32_16x16x32_bf16(A2, B2, corr[lt][0], 0, 0, 0);
                }
            }
            #pragma unroll
            for (int lt = 0; lt < 4; ++lt)
                #pragma unroll
                for (int reg = 0; reg < 4; ++reg)
                    s64[lt][reg] += (double)accm[lt][reg];
        }
        const int is_k = (o0 >= 1024);
        const double g  = (double)(is_k ? gamma_k[0] : gamma_q[0]);
        const double be = (double)(is_k ? beta_k[0]  : beta_q[0]);
        const int o_global = osub + m;
        const int o_local  = o_global - (is_k ? 1024 : 0);
        const double bias  = (double)(is_k ? k_b[o_local] : q_b[o_local]);
        float* dest = is_k ? k_s : q_s;
        #pragma unroll
        for (int lt = 0; lt < 4; ++lt) {
            #pragma unroll
            for (int reg = 0; reg < 4; ++reg) {
                double s = (double)corr[lt][0][reg] + (double)corr[lt][1][reg]
                         + s64[lt][reg];
                const int l = lb0 + lt*16 + quad*4 + reg;
                dest[((size_t)(b*LL + l))*OC + o_local] = (float)(g*(s + bias) + be);
            }
        }
    } else {
        const int o0 = (yt - 32) << 6;
        const int osub = o0 + wave*16;
        float4v corr[4];                    // 16 AGPR
        float4v accm[4];                    // 16 AGPR
        double  sv[4][4];                   // fp64 running chunk sums
        #pragma unroll
        for (int lt = 0; lt < 4; ++lt) {
            corr[lt] = (float4v){0.f,0.f,0.f,0.f};
            #pragma unroll
            for (int reg = 0; reg < 4; ++reg) sv[lt][reg] = 0.0;
        }
        #pragma unroll
        for (int cidx = 0; cidx < 4; ++cidx) {
            const int c0 = cidx << 5;
            #pragma unroll
            for (int lt = 0; lt < 4; ++lt) accm[lt] = (float4v){0.f,0.f,0.f,0.f};
            size_t base = ((size_t)(osub + m))*128 + c0 + quad*8;
            bf16x8 B1 = *(const bf16x8*)&venc[base];
            bf16x8 B2 = *(const bf16x8*)&venc[base + (size_t)1024*128];
            #pragma unroll
            for (int lt = 0; lt < 4; ++lt) {
                const int row = lt*16 + m + 2;
                bf16x8 A1 = *(const bf16x8*)&As[0][row][c0 + quad*8];
                bf16x8 A2 = *(const bf16x8*)&As[1][row][c0 + quad*8];
                accm[lt] = __builtin_amdgcn_mfma_f32_16x16x32_bf16(A1, B1, accm[lt], 0, 0, 0);
                corr[lt] = __builtin_amdgcn_mfma_f32_16x16x32_bf16(A1, B2, corr[lt], 0, 0, 0);
                corr[lt] = __builtin_amdgcn_mfma_f32_16x16x32_bf16(A2, B1, corr[lt], 0, 0, 0);
                corr[lt] = __builtin_amdgcn_mfma_f32_16x16x32_bf16(A2, B2, corr[lt], 0, 0, 0);
            }
            #pragma unroll
            for (int lt = 0; lt < 4; ++lt)
                #pragma unroll
                for (int reg = 0; reg < 4; ++reg)
                    sv[lt][reg] += (double)accm[lt][reg];
        }
        const int o_local = osub + m;
        #pragma unroll
        for (int lt = 0; lt < 4; ++lt) {
            #pragma unroll
            for (int reg = 0; reg < 4; ++reg) {
                float s = (float)(sv[lt][reg] + (double)corr[lt][reg]);
                const int l = lb0 + lt*16 + quad*4 + reg;
                v_s[((size_t)(b*LL + l))*OC + o_local] = s;
            }
        }
    }
}

// ---------------------------------------------------------------------------
// Kernel 2: sketch q+k fused, 3-plane/6-pass MFMA in-place; fast_phi epilogue.
// r22: float4 staging loads (values/placement identical).
// ---------------------------------------------------------------------------
__global__ __launch_bounds__(256) void sketch_mfma_k(
    float* __restrict__ q_s, float* __restrict__ k_s,
    const __bf16* __restrict__ genc_all)
{
    __shared__ __bf16 As[3][32][136];
    const int tid  = threadIdx.x;
    const int wave = tid >> 6;
    const int lane = tid & 63;
    const int m    = lane & 15;
    const int quad = lane >> 4;
    const int half = blockIdx.x >> 10;
    float* buf = half ? k_s : q_s;
    const __bf16* genc = genc_all + (size_t)half*2*3*128*128;
    const size_t i0 = (size_t)(blockIdx.x & 1023) * 32;

    for (int e = tid; e < 32*32; e += 256) {
        const int row = e >> 5, d0 = (e & 31) << 2;
        const float4 v4 = *(const float4*)&buf[(i0 + row)*RR_ + d0];
        const float vs[4] = {v4.x, v4.y, v4.z, v4.w};
        #pragma unroll
        for (int j = 0; j < 4; ++j) {
            float v = vs[j];
            __bf16 h1 = (__bf16)v;  float r1 = v - (float)h1;
            __bf16 h2 = (__bf16)r1; float r2 = r1 - (float)h2;
            __bf16 h3 = (__bf16)r2;
            As[0][row][d0+j] = h1; As[1][row][d0+j] = h2; As[2][row][d0+j] = h3;
        }
    }
    __syncthreads();

    float4v accm[2][2][2], corr[2][2][2];
    #pragma unroll
    for (int mt = 0; mt < 2; ++mt)
        #pragma unroll
        for (int nt = 0; nt < 2; ++nt)
            #pragma unroll
            for (int mat = 0; mat < 2; ++mat) {
                accm[mt][nt][mat] = (float4v){0.f,0.f,0.f,0.f};
                corr[mt][nt][mat] = (float4v){0.f,0.f,0.f,0.f};
            }

    #pragma unroll
    for (int ck = 0; ck < 4; ++ck) {
        const int k0 = ck << 5;
        bf16x8 A1[2], A2[2], A3[2];
        #pragma unroll
        for (int mt = 0; mt < 2; ++mt) {
            A1[mt] = *(const bf16x8*)&As[0][mt*16 + m][k0 + quad*8];
            A2[mt] = *(const bf16x8*)&As[1][mt*16 + m][k0 + quad*8];
            A3[mt] = *(const bf16x8*)&As[2][mt*16 + m][k0 + quad*8];
        }
        #pragma unroll
        for (int nt = 0; nt < 2; ++nt) {
            const int r = wave*32 + nt*16 + m;
            #pragma unroll
            for (int mat = 0; mat < 2; ++mat) {
                size_t base = ((size_t)(mat*3)*128 + r)*128 + k0 + quad*8;
                bf16x8 B1 = *(const bf16x8*)&genc[base];
                bf16x8 B2 = *(const bf16x8*)&genc[base + (size_t)128*128];
                bf16x8 B3 = *(const bf16x8*)&genc[base + (size_t)2*128*128];
                #pragma unroll
                for (int mt = 0; mt < 2; ++mt) {
                    accm[mt][nt][mat] = __builtin_amdgcn_mfma_f32_16x16x32_bf16(A1[mt], B1, accm[mt][nt][mat], 0, 0, 0);
                    corr[mt][nt][mat] = __builtin_amdgcn_mfma_f32_16x16x32_bf16(A1[mt], B2, corr[mt][nt][mat], 0, 0, 0);
                    corr[mt][nt][mat] = __builtin_amdgcn_mfma_f32_16x16x32_bf16(A2[mt], B1, corr[mt][nt][mat], 0, 0, 0);
                    corr[mt][nt][mat] = __builtin_amdgcn_mfma_f32_16x16x32_bf16(A1[mt], B3, corr[mt][nt][mat], 0, 0, 0);
                    corr[mt][nt][mat] = __builtin_amdgcn_mfma_f32_16x16x32_bf16(A3[mt], B1, corr[mt][nt][mat], 0, 0, 0);
                    corr[mt][nt][mat] = __builtin_amdgcn_mfma_f32_16x16x32_bf16(A2[mt], B2, corr[mt][nt][mat], 0, 0, 0);
                }
            }
        }
    }
    __syncthreads();

    #pragma unroll
    for (int mt = 0; mt < 2; ++mt)
        #pragma unroll
        for (int nt = 0; nt < 2; ++nt)
            #pragma unroll
            for (int reg = 0; reg < 4; ++reg) {
                double u1 = (double)accm[mt][nt][0][reg] + (double)corr[mt][nt][0][reg];
                double u2 = (double)accm[mt][nt][1][reg] + (double)corr[mt][nt][1][reg];
                const size_t row = i0 + mt*16 + quad*4 + reg;
                const int col = wave*32 + nt*16 + m;
                buf[row*RR_ + col] = fast_phi(u1, u2);
            }
}

// ---------------------------------------------------------------------------
// Kernel 3: KV^T partials via 2-plane MFMA + fp64 Ksum partials (r10-proven).
// Staging left scalar: per-thread ks is keyed to r = tid&127 (part_ks is a
// per-feature column sum) -- float4 would mix r values and corrupt it.
// ---------------------------------------------------------------------------
__global__ __launch_bounds__(512) void kv_mfma_k(
    const float* __restrict__ phi_k, const float* __restrict__ v,
    float* __restrict__ part_kv, double* __restrict__ part_ks)
{
    __shared__ float Pt[128*36];
    __shared__ float Vt[128*36];
    __shared__ double ksred[512];
    const int tid  = threadIdx.x;
    const int wave = tid >> 6;
    const int lane = tid & 63;
    const int m    = lane & 15;
    const int quad = lane >> 4;
    const int split = blockIdx.x;
    const int bh    = blockIdx.y;
    const int b = bh >> 3, h = bh & 7;
    const int lbase = split * 128;
    const int dh = wave & 1;
    const int rq = wave >> 1;

    float4v accm[4][2], corr[4][2];
    #pragma unroll
    for (int mt = 0; mt < 4; ++mt)
        #pragma unroll
        for (int nt = 0; nt < 2; ++nt) {
            accm[mt][nt] = (float4v){0.f,0.f,0.f,0.f};
            corr[mt][nt] = (float4v){0.f,0.f,0.f,0.f};
        }
    double ks = 0.0;

    for (int ch = 0; ch < 4; ++ch) {
        __syncthreads();
        for (int e = tid; e < 32*128; e += 512) {
            const int l = e >> 7, r = e & 127;
            size_t base = ((size_t)(b*LL + lbase + ch*32 + l)*HH + h)*RR_;
            float pv = phi_k[base + r];
            float vv = v[base + r];
            Pt[r*36 + l] = pv;
            Vt[r*36 + l] = vv;
            ks += (double)pv;
        }
        __syncthreads();
        bf16x8 A1[4], A2[4], B1[2], B2[2];
        #pragma unroll
        for (int mt = 0; mt < 4; ++mt)
            enc2(&Vt[(dh*64 + mt*16 + m)*36 + quad*8], A1[mt], A2[mt]);
        #pragma unroll
        for (int nt = 0; nt < 2; ++nt)
            enc2(&Pt[(rq*32 + nt*16 + m)*36 + quad*8], B1[nt], B2[nt]);
        #pragma unroll
        for (int mt = 0; mt < 4; ++mt)
            #pragma unroll
            for (int nt = 0; nt < 2; ++nt) {
                accm[mt][nt] = __builtin_amdgcn_mfma_f32_16x16x32_bf16(A1[mt], B1[nt], accm[mt][nt], 0, 0, 0);
                corr[mt][nt] = __builtin_amdgcn_mfma_f32_16x16x32_bf16(A1[mt], B2[nt], corr[mt][nt], 0, 0, 0);
                corr[mt][nt] = __builtin_amdgcn_mfma_f32_16x16x32_bf16(A2[mt], B1[nt], corr[mt][nt], 0, 0, 0);
                corr[mt][nt] = __builtin_amdgcn_mfma_f32_16x16x32_bf16(A2[mt], B2[nt], corr[mt][nt], 0, 0, 0);
            }
    }

    ksred[tid] = ks;
    __syncthreads();
    if (tid < 128) {
        double s = ksred[tid] + ksred[tid+128] + ksred[tid+256] + ksred[tid+384];
        part_ks[(bh*16 + split)*RR_ + tid] = s;
    }

    float* outp = part_kv + ((size_t)(bh*16 + split))*RR_*DD;
    #pragma unroll
    for (int mt = 0; mt < 4; ++mt)
        #pragma unroll
        for (int nt = 0; nt < 2; ++nt)
            #pragma unroll
            for (int reg = 0; reg < 4; ++reg) {
                const int d = dh*64 + mt*16 + quad*4 + reg;
                const int r = rq*32 + nt*16 + m;
                outp[d*128 + r] = accm[mt][nt][reg] + corr[mt][nt][reg];
            }
}

// ---------------------------------------------------------------------------
// Kernel 4: reduce KVT partials -> bf16 2-plane KVTenc.
// ---------------------------------------------------------------------------
__global__ __launch_bounds__(256) void kvreduce_k(
    const float* __restrict__ part_kv, __bf16* __restrict__ kvt_enc)
{
    const int gid = blockIdx.x*256 + threadIdx.x;
    if (gid >= 16*RR_*DD) return;
    const int bh = gid >> 14;
    const int rd = gid & 16383;
    float s = 0.f;
    #pragma unroll
    for (int c = 0; c < 16; ++c)
        s += part_kv[(((size_t)(bh*16 + c)) << 14) + rd];
    __bf16 h1 = (__bf16)s;
    __bf16 h2 = (__bf16)(s - (float)h1);
    kvt_enc[(size_t)bh*16384 + rd] = h1;
    kvt_enc[(size_t)(16 + bh)*16384 + rd] = h2;
}

// ---------------------------------------------------------------------------
// Kernel 5: numerator MFMA + fp64 den (r10-proven). r22: float4 staging.
// ---------------------------------------------------------------------------
__global__ __launch_bounds__(256) void numden_mfma_k(
    const float* __restrict__ phi_q, const __bf16* __restrict__ kvt_enc,
    const double* __restrict__ part_ks, float* __restrict__ o_out)
{
    __shared__ float Pq[64*132];
    __shared__ double Ks_s[128];
    __shared__ double den_s[64];
    const int tid  = threadIdx.x;
    const int wave = tid >> 6;
    const int lane = tid & 63;
    const int m    = lane & 15;
    const int quad = lane >> 4;
    const int lt = blockIdx.x;
    const int bh = blockIdx.y;
    const int b = bh >> 3, h = bh & 7;
    const int l0 = lt * 64;

    if (tid < 128) {
        double s = 0.0;
        #pragma unroll
        for (int c = 0; c < 16; ++c) s += part_ks[(bh*16 + c)*RR_ + tid];
        Ks_s[tid] = s;
    }
    for (int e = tid; e < 64*32; e += 256) {
        const int l = e >> 5, r0 = (e & 31) << 2;
        *(float4*)&Pq[l*132 + r0] =
            *(const float4*)&phi_q[((size_t)(b*LL + l0 + l)*HH + h)*RR_ + r0];
    }
    __syncthreads();

    double den = 0.0;
    if (tid < 64) {
        #pragma unroll
        for (int r = 0; r < 128; ++r)
            den += (double)Pq[tid*132 + r] * Ks_s[r];
    }

    float4v accm[4][2], corr[4][2];
    #pragma unroll
    for (int mt = 0; mt < 4; ++mt)
        #pragma unroll
        for (int nt = 0; nt < 2; ++nt) {
            accm[mt][nt] = (float4v){0.f,0.f,0.f,0.f};
            corr[mt][nt] = (float4v){0.f,0.f,0.f,0.f};
        }

    #pragma unroll
    for (int ck = 0; ck < 4; ++ck) {
        const int k0 = ck << 5;
        bf16x8 A1[4], A2[4];
        #pragma unroll
        for (int mt = 0; mt < 4; ++mt)
            enc2(&Pq[(mt*16 + m)*132 + k0 + quad*8], A1[mt], A2[mt]);
        #pragma unroll
        for (int nt = 0; nt < 2; ++nt) {
            const int d = wave*32 + nt*16 + m;
            size_t base = ((size_t)bh*128 + d)*128 + k0 + quad*8;
            bf16x8 B1 = *(const bf16x8*)&kvt_enc[base];
            bf16x8 B2 = *(const bf16x8*)&kvt_enc[base + (size_t)16*16384];
            #pragma unroll
            for (int mt = 0; mt < 4; ++mt) {
                accm[mt][nt] = __builtin_amdgcn_mfma_f32_16x16x32_bf16(A1[mt], B1, accm[mt][nt], 0, 0, 0);
                corr[mt][nt] = __builtin_amdgcn_mfma_f32_16x16x32_bf16(A1[mt], B2, corr[mt][nt], 0, 0, 0);
                corr[mt][nt] = __builtin_amdgcn_mfma_f32_16x16x32_bf16(A2[mt], B1, corr[mt][nt], 0, 0, 0);
                corr[mt][nt] = __builtin_amdgcn_mfma_f32_16x16x32_bf16(A2[mt], B2, corr[mt][nt], 0, 0, 0);
            }
        }
    }

    __syncthreads();
    if (tid < 64) den_s[tid] = den;
    __syncthreads();

    #pragma unroll
    for (int mt = 0; mt < 4; ++mt)
        #pragma unroll
        for (int nt = 0; nt < 2; ++nt)
            #pragma unroll
            for (int reg = 0; reg < 4; ++reg) {
                const int ll = mt*16 + quad*4 + reg;
                const int d  = wave*32 + nt*16 + m;
                const float inv = (float)(1.0 / (den_s[ll] + 1e-6));
                o_out[((size_t)(b*LL + l0 + ll))*OC + h*DD + d] =
                    (accm[mt][nt][reg] + corr[mt][nt][reg]) * inv;
            }
}

// ---------------------------------------------------------------------------
// Kernel 6: output projection partials via 2-plane MFMA (r10-proven).
// r22: float4 staging.
// ---------------------------------------------------------------------------
__global__ __launch_bounds__(256) void proj_part_mfma_k(
    const float* __restrict__ o_s, const __bf16* __restrict__ penc,
    float* __restrict__ part)
{
    __shared__ float As[32*260];
    const int tid  = threadIdx.x;
    const int wave = tid >> 6;
    const int lane = tid & 63;
    const int m    = lane & 15;
    const int quad = lane >> 4;
    const int row0  = blockIdx.x * 32;
    const int kbase = blockIdx.y * 256;

    for (int e = tid; e < 32*64; e += 256) {
        const int row = e >> 6, k0 = (e & 63) << 2;
        *(float4*)&As[row*260 + k0] =
            *(const float4*)&o_s[(size_t)(row0 + row)*OC + kbase + k0];
    }
    __syncthreads();

    float4v accm[2][2], corr[2][2];
    #pragma unroll
    for (int mt = 0; mt < 2; ++mt)
        #pragma unroll
        for (int nt = 0; nt < 2; ++nt) {
            accm[mt][nt] = (float4v){0.f,0.f,0.f,0.f};
            corr[mt][nt] = (float4v){0.f,0.f,0.f,0.f};
        }

    #pragma unroll
    for (int ck = 0; ck < 8; ++ck) {
        const int k0 = ck << 5;
        bf16x8 A1[2], A2[2];
        #pragma unroll
        for (int mt = 0; mt < 2; ++mt)
            enc2(&As[(mt*16 + m)*260 + k0 + quad*8], A1[mt], A2[mt]);
        #pragma unroll
        for (int nt = 0; nt < 2; ++nt) {
            const int j = wave*32 + nt*16 + m;
            size_t base = ((size_t)j)*OC + kbase + k0 + quad*8;
            bf16x8 B1 = *(const bf16x8*)&penc[base];
            bf16x8 B2 = *(const bf16x8*)&penc[base + (size_t)128*OC];
            #pragma unroll
            for (int mt = 0; mt < 2; ++mt) {
                accm[mt][nt] = __builtin_amdgcn_mfma_f32_16x16x32_bf16(A1[mt], B1, accm[mt][nt], 0, 0, 0);
                corr[mt][nt] = __builtin_amdgcn_mfma_f32_16x16x32_bf16(A1[mt], B2, corr[mt][nt], 0, 0, 0);
                corr[mt][nt] = __builtin_amdgcn_mfma_f32_16x16x32_bf16(A2[mt], B1, corr[mt][nt], 0, 0, 0);
                corr[mt][nt] = __builtin_amdgcn_mfma_f32_16x16x32_bf16(A2[mt], B2, corr[mt][nt], 0, 0, 0);
            }
        }
    }

    float* outp = part + (size_t)blockIdx.y*BL*DD;
    #pragma unroll
    for (int mt = 0; mt < 2; ++mt)
        #pragma unroll
        for (int nt = 0; nt < 2; ++nt)
            #pragma unroll
            for (int reg = 0; reg < 4; ++reg) {
                const int row = row0 + mt*16 + quad*4 + reg;
                const int j   = wave*32 + nt*16 + m;
                outp[(size_t)row*DD + j] = accm[mt][nt][reg] + corr[mt][nt][reg];
            }
}

// ---------------------------------------------------------------------------
// Kernel 7: reduce the 4 K-split partials + bias.
// ---------------------------------------------------------------------------
__global__ __launch_bounds__(256) void proj_reduce_k(
    const float* __restrict__ part, const float* __restrict__ pb,
    float* __restrict__ out)
{
    const int gid = blockIdx.x*256 + threadIdx.x;
    if (gid >= BL*DD/4) return;
    const float4* p4 = (const float4*)part;
    float4 s = p4[gid];
    #pragma unroll
    for (int c = 1; c < 4; ++c) {
        float4 t = p4[gid + (size_t)c*(BL*DD/4)];
        s.x += t.x; s.y += t.y; s.z += t.z; s.w += t.w;
    }
    const int col = (gid << 2) & (DD-1);
    s.x += pb[col]; s.y += pb[col+1]; s.z += pb[col+2]; s.w += pb[col+3];
    ((float4*)out)[gid] = s;
}

// ---------------------------------------------------------------------------
extern "C" void kernel_launch(void* const* d_in, const int* in_sizes, int n_in,
                              void* d_out, int out_size, void* d_ws, size_t ws_size,
                              hipStream_t stream) {
    const float* x       = (const float*)d_in[0];
    const float* q_w     = (const float*)d_in[1];
    const float* q_b     = (const float*)d_in[2];
    const float* k_w     = (const float*)d_in[3];
    const float* k_b     = (const float*)d_in[4];
    const float* v_w     = (const float*)d_in[5];
    const float* g1_q    = (const float*)d_in[6];
    const float* g2_q    = (const float*)d_in[7];
    const float* g1_k    = (const float*)d_in[8];
    const float* g2_k    = (const float*)d_in[9];
    const float* gamma_q = (const float*)d_in[10];
    const float* beta_q  = (const float*)d_in[11];
    const float* gamma_k = (const float*)d_in[12];
    const float* beta_k  = (const float*)d_in[13];
    const float* proj_w  = (const float*)d_in[14];
    const float* proj_b  = (const float*)d_in[15];

    float* f = (float*)d_ws;
    float* q_s     = f;                        // 4,194,304 floats
    float* k_s     = f + 4194304;              // 4,194,304
    float* v_s     = f + 8388608;              // 4,194,304
    float* part_kv = f + 12582912;             // 4,194,304 (scratch: wenc/xenc/kv parts/proj parts)
    double* part_ks = (double*)(f + 16777216); // 32,768 doubles
    __bf16* kvt_enc = (__bf16*)(f + 16842752); // 524,288 bf16
    __bf16* genc   = (__bf16*)(f + 17104896);  // 196,608 bf16
    __bf16* venc   = (__bf16*)(f + 17203200);  // 262,144 bf16
    __bf16* penc   = (__bf16*)(f + 17334272);  // 262,144 bf16
    float* o_s     = k_s;                      // reuse (phi_k dead after kv_mfma)
    float* proj_part = part_kv;                // reuse (kv parts dead after kvreduce)
    __bf16* wenc   = (__bf16*)(f + 12582912);
    __bf16* xenc   = (__bf16*)(f + 13762560);

    dim3 blk(256);
    enc_fused_k<<<2816, blk, 0, stream>>>(q_w, k_w, v_w, proj_w,
                                          g1_q, g2_q, g1_k, g2_k, x,
                                          wenc, genc, venc, penc, xenc);
    conv_mfma_k<<<dim3(64,48), blk, 0, stream>>>(xenc, wenc, venc, q_b, k_b,
                                                 gamma_q, beta_q, gamma_k, beta_k,
                                                 q_s, k_s, v_s);
    sketch_mfma_k<<<2048, blk, 0, stream>>>(q_s, k_s, genc);
    kv_mfma_k<<<dim3(16,16), dim3(512), 0, stream>>>(k_s, v_s, part_kv, part_ks);
    kvreduce_k<<<1024, blk, 0, stream>>>(part_kv, kvt_enc);
    numden_mfma_k<<<dim3(32,16), blk, 0, stream>>>(q_s, kvt_enc, part_ks, o_s);
    proj_part_mfma_k<<<dim3(128,4), blk, 0, stream>>>(o_s, penc, proj_part);
    proj_reduce_k<<<512, blk, 0, stream>>>(proj_part, proj_b, (float*)d_out);
}

// Round 6
// 255.237 us; speedup vs baseline: 1.1287x; 1.0386x over previous
//
#include <hip/hip_runtime.h>
#include <math.h>

// Problem constants
#define BB 2
#define DD 128
#define LL 2048
#define HH 8
#define OC 1024     // H*D
#define RR_ 128
#define BL (BB*LL)          // 4096
#define NROW (BL*HH)        // 32768
#define XROWS 2052

// Numerics ledger (absmax bf16-quantized; threshold 180.48):
//   r3 full fp64 -> 128 PASS | r2 seq fp32 -> 192 FAIL | r5 tanhf -> FAIL
//   r6 chunk4/8+fp64 tanh -> 128 PASS | r7-r11 MFMA ladder -> 64 PASS
//   r14 -> 64 PASS, 268us | r15 4x o-tile -> spill REGRESS | r16 267us
//   r17 B-dbuf neutral | r18 repart+reg-dbuf -> FAIL post-timing divergence
//   r19 repart 32lx32o -> conv 108us REGRESS (B-traffic x2 at fixed occ)
//   r20 lb(256,3): VGPR 80, occ STILL 2 blk -> conv 72.8 (pressure relief)
//   r21 8-wave: occ 41% but conv 96us REGRESS (per-wave MFMA run halved)
//   r22 acc-fold (AGPR 96->48, unified 120) + lb(256,3): VGPR 72 but occ
//   STILL 19.5% -> LDS is the cap: 3x54272=162816 > usable (~<163840 after
//   HW reserve). Conv 72.9; total 265.1 (float4 staging kept).
// r23: chunk-staged double-buffered As[2][3][66][40] = 31,680 B/block
//      (80B row stride 16B-aligned; 20-dword bank stride = free 2-way).
//      LDS now admits 5 blocks; regs (120) admit 4 waves/SIMD -> 3-4 blk/CU.
//      Loop shape per wave unchanged (3 B-loads : 24 MFMA per round);
//      MFMA chain order identical to r22 -> bit-identical, absmax 64.
//      v-branch stages planes 0-1 only.

typedef __bf16  bf16x8  __attribute__((ext_vector_type(8)));
typedef __bf16  bf16x4  __attribute__((ext_vector_type(4)));
typedef float   float4v __attribute__((ext_vector_type(4)));

__device__ __forceinline__ void enc2(const float* src, bf16x8& p1, bf16x8& p2) {
    #pragma unroll
    for (int j = 0; j < 8; ++j) {
        float v = src[j];
        __bf16 h1 = (__bf16)v;
        p1[j] = h1;
        p2[j] = (__bf16)(v - (float)h1);
    }
}

// phi = SR*tanh(u1*u2/SR) = SR*(1 - 2/(2^y + 1)), y = u1*u2*(2/sqrt(128))*log2e.
__device__ __forceinline__ float fast_phi(double u1, double u2) {
    const double TWO_ISR = 0.17677669529663688110;  // 2/sqrt(128) = sqrt(2)/8
    const double LOG2E   = 1.44269504088896340736;  // log2(e)
    const double SR      = 11.313708498984760390;   // sqrt(128)
    double y = (u1*u2) * (TWO_ISR * LOG2E);
    y = fmin(fmax(y, -1020.4), 1020.4);
    double n = rint(y);
    double f = y - n;
    float ff = (float)f;
    float q;
    q = fmaf(1.01780860092396960e-7f, ff, 1.32154867901443094e-6f);
    q = fmaf(q, ff, 1.52527338040598403e-5f);
    q = fmaf(q, ff, 1.54035303933816099e-4f);
    q = fmaf(q, ff, 1.33335581464284434e-3f);
    q = fmaf(q, ff, 9.61812910762847716e-3f);
    q = fmaf(q, ff, 5.55041086648215800e-2f);
    double t2   = fma(f, (double)q, 0.24022650695910071233);
    double head = fma(f, 0.69314718055994530942, 1.0);
    double E0   = fma(f*f, t2, head);
    int ni = (int)n;
    double En = __hiloint2double((ni + 1023) << 20, 0);   // 2^n
    double E  = E0 * En;
    double den = E + 1.0;
    double r = (double)__builtin_amdgcn_rcpf((float)den);
    r = r * fma(-den, r, 2.0);
    r = r * fma(-den, r, 2.0);
    double t = fma(-2.0, r, 1.0);
    return (float)(SR * t);
}

// ---------------------------------------------------------------------------
// Kernel 0: fused encode (weights + x). (r11-proven)
// ---------------------------------------------------------------------------
__global__ __launch_bounds__(256) void enc_fused_k(
    const float* __restrict__ q_w, const float* __restrict__ k_w,
    const float* __restrict__ v_w, const float* __restrict__ pw,
    const float* __restrict__ g1_q, const float* __restrict__ g2_q,
    const float* __restrict__ g1_k, const float* __restrict__ g2_k,
    const float* __restrict__ x,
    __bf16* __restrict__ wenc, __bf16* __restrict__ genc,
    __bf16* __restrict__ venc, __bf16* __restrict__ penc,
    __bf16* __restrict__ xenc)
{
    __shared__ float t[32][33];
    const int bid = blockIdx.x;
    const int tid = threadIdx.x;
    if (bid < 2304) {
        const int gid = bid*256 + tid;
        if (gid < 262144) {
            const int o = gid >> 7, c = gid & 127;
            #pragma unroll
            for (int tt = 0; tt < 3; ++tt) {
                float v = (o < 1024) ? q_w[(o*128 + c)*3 + tt]
                                     : k_w[((o-1024)*128 + c)*3 + tt];
                __bf16 h1 = (__bf16)v;  float r1 = v - (float)h1;
                __bf16 h2 = (__bf16)r1; float r2 = r1 - (float)h2;
                __bf16 h3 = (__bf16)r2;
                wenc[((size_t)(0*3 + tt)*2048 + o)*128 + c] = h1;
                wenc[((size_t)(1*3 + tt)*2048 + o)*128 + c] = h2;
                wenc[((size_t)(2*3 + tt)*2048 + o)*128 + c] = h3;
            }
        } else if (gid < 262144 + 65536) {
            const int g = gid - 262144;
            const int mat = g >> 14, rem = g & 16383;
            const int r = rem >> 7, d = rem & 127;
            const float* src = (mat == 0) ? g1_q : (mat == 1) ? g2_q
                             : (mat == 2) ? g1_k : g2_k;
            float v = src[d*RR_ + r];
            __bf16 h1 = (__bf16)v;  float r1 = v - (float)h1;
            __bf16 h2 = (__bf16)r1; float r2 = r1 - (float)h2;
            __bf16 h3 = (__bf16)r2;
            genc[((size_t)(mat*3 + 0)*128 + r)*128 + d] = h1;
            genc[((size_t)(mat*3 + 1)*128 + r)*128 + d] = h2;
            genc[((size_t)(mat*3 + 2)*128 + r)*128 + d] = h3;
        } else if (gid < 262144 + 65536 + 131072) {
            const int g = gid - 262144 - 65536;
            const int o = g >> 7, c = g & 127;
            float v = v_w[o*128 + c];
            __bf16 h1 = (__bf16)v;  float r1 = v - (float)h1;
            __bf16 h2 = (__bf16)r1;
            venc[((size_t)0*1024 + o)*128 + c] = h1;
            venc[((size_t)1*1024 + o)*128 + c] = h2;
        } else if (gid < 262144 + 65536 + 131072 + 131072) {
            const int g = gid - 262144 - 65536 - 131072;
            const int j = g >> 10, k = g & 1023;
            float v = pw[(size_t)j*OC + k];
            __bf16 h1 = (__bf16)v;  float r1 = v - (float)h1;
            __bf16 h2 = (__bf16)r1;
            penc[((size_t)(0*128 + j))*OC + k] = h1;
            penc[((size_t)(1*128 + j))*OC + k] = h2;
        }
    } else {
        const int g = bid - 2304;
        const int lt = g & 63, ct = (g >> 6) & 3, b = g >> 8;
        const int l0 = lt*32, c0 = ct*32;
        for (int e = tid; e < 32*32; e += 256) {
            int c = e >> 5, l = e & 31;
            t[c][l] = x[((size_t)(b*DD + c0 + c))*LL + l0 + l];
        }
        __syncthreads();
        for (int e = tid; e < 32*32; e += 256) {
            int l = e >> 5, c = e & 31;
            float v = t[c][l];
            __bf16 h1 = (__bf16)v;  float r1 = v - (float)h1;
            __bf16 h2 = (__bf16)r1; float r2 = r1 - (float)h2;
            __bf16 h3 = (__bf16)r2;
            const size_t row = (size_t)(l0 + l + 2);
            xenc[((size_t)(0*2 + b)*XROWS + row)*128 + c0 + c] = h1;
            xenc[((size_t)(1*2 + b)*XROWS + row)*128 + c0 + c] = h2;
            xenc[((size_t)(2*2 + b)*XROWS + row)*128 + c0 + c] = h3;
        }
        if (lt == 0 && ct == 0) {
            for (int e = tid; e < 2*128; e += 256) {
                int row = e >> 7, c = e & 127;
                xenc[((size_t)(0*2 + b)*XROWS + row)*128 + c] = (__bf16)0.f;
                xenc[((size_t)(1*2 + b)*XROWS + row)*128 + c] = (__bf16)0.f;
                xenc[((size_t)(2*2 + b)*XROWS + row)*128 + c] = (__bf16)0.f;
            }
        }
    }
}

// ---------------------------------------------------------------------------
// Kernel 1: fused q+k conv (3-plane/6-pass) AND v (2-plane/4-pass).
// r23: chunk-staged double-buffered LDS. As[2][3][66][40] = 31,680 B.
// Iteration cidx: read buf[cidx&1], prefetch chunk cidx+1 into buf[^1],
// one barrier at loop end (protects next-read of prefetched buf AND
// next-write of the buf just read). Wave structure and per-accumulator
// MFMA chain identical to r22 -> bit-identical arithmetic.
// grid (64, 48): y<32 -> q|k conv o-tile, y>=32 -> v o-tile.
// ---------------------------------------------------------------------------
__global__ __launch_bounds__(256, 3) void conv_mfma_k(
    const __bf16* __restrict__ xenc, const __bf16* __restrict__ wenc,
    const __bf16* __restrict__ venc,
    const float* __restrict__ q_b, const float* __restrict__ k_b,
    const float* __restrict__ gamma_q, const float* __restrict__ beta_q,
    const float* __restrict__ gamma_k, const float* __restrict__ beta_k,
    float* __restrict__ q_s, float* __restrict__ k_s, float* __restrict__ v_s)
{
    __shared__ __bf16 As[2][3][66][40];
    const int tid  = threadIdx.x;
    const int wave = tid >> 6;
    const int lane = tid & 63;
    const int m    = lane & 15;
    const int quad = lane >> 4;
    const int bx = blockIdx.x;
    const int b  = bx >> 5;
    const int lb0 = (bx & 31) << 6;
    const int yt = blockIdx.y;
    const int is_conv = (yt < 32);
    const int np = is_conv ? 3 : 2;          // v uses planes 0,1 only

    // stage chunk 0 -> buffer 0
    for (int e = tid; e < np*66*4; e += 256) {
        const int p = e / (66*4), rem = e % (66*4);
        const int row = rem >> 2, cg = rem & 3;
        *(bf16x8*)&As[0][p][row][cg*8] =
            *(const bf16x8*)&xenc[((size_t)(p*2 + b)*XROWS + lb0 + row)*128 + cg*8];
    }
    __syncthreads();

    if (is_conv) {
        const int o0 = yt << 6;
        const int osub = o0 + wave*16;
        float4v corr[4][2];                 // 32 AGPR
        float4v accm[4];                    // 16 AGPR (per-chunk)
        double  s64[4][4];                  // fp64 running chunk sums
        #pragma unroll
        for (int lt = 0; lt < 4; ++lt) {
            corr[lt][0] = (float4v){0.f,0.f,0.f,0.f};
            corr[lt][1] = (float4v){0.f,0.f,0.f,0.f};
            #pragma unroll
            for (int reg = 0; reg < 4; ++reg) s64[lt][reg] = 0.0;
        }
        #pragma unroll
        for (int cidx = 0; cidx < 4; ++cidx) {
            const int cur = cidx & 1;
            if (cidx < 3) {
                const int nc0 = (cidx + 1) << 5;
                for (int e = tid; e < 3*66*4; e += 256) {
                    const int p = e / (66*4), rem = e % (66*4);
                    const int row = rem >> 2, cg = rem & 3;
                    *(bf16x8*)&As[cur ^ 1][p][row][cg*8] =
                        *(const bf16x8*)&xenc[((size_t)(p*2 + b)*XROWS + lb0 + row)*128 + nc0 + cg*8];
                }
            }
            const int c0 = cidx << 5;
            #pragma unroll
            for (int lt = 0; lt < 4; ++lt) accm[lt] = (float4v){0.f,0.f,0.f,0.f};
            #pragma unroll
            for (int t = 0; t < 3; ++t) {
                size_t base = ((size_t)t*2048 + osub + m)*128 + c0 + quad*8;
                bf16x8 B1 = *(const bf16x8*)&wenc[base];
                bf16x8 B2 = *(const bf16x8*)&wenc[base + (size_t)3*2048*128];
                bf16x8 B3 = *(const bf16x8*)&wenc[base + (size_t)6*2048*128];
                #pragma unroll
                for (int lt = 0; lt < 4; ++lt) {
                    const int row = lt*16 + m + t;
                    bf16x8 A1 = *(const bf16x8*)&As[cur][0][row][quad*8];
                    bf16x8 A2 = *(const bf16x8*)&As[cur][1][row][quad*8];
                    bf16x8 A3 = *(const bf16x8*)&As[cur][2][row][quad*8];
                    accm[lt]    = __builtin_amdgcn_mfma_f32_16x16x32_bf16(A1, B1, accm[lt], 0, 0, 0);
                    corr[lt][0] = __builtin_amdgcn_mfma_f32_16x16x32_bf16(A1, B2, corr[lt][0], 0, 0, 0);
                    corr[lt][1] = __builtin_amdgcn_mfma_f32_16x16x32_bf16(A2, B1, corr[lt][1], 0, 0, 0);
                    corr[lt][0] = __builtin_amdgcn_mfma_f32_16x16x32_bf16(A1, B3, corr[lt][0], 0, 0, 0);
                    corr[lt][1] = __builtin_amdgcn_mfma_f32_16x16x32_bf16(A3, B1, corr[lt][1], 0, 0, 0);
                    corr[lt][0] = __builtin_amdgcn_mfma_f32_16x16x32_bf16(A2, B2, corr[lt][0], 0, 0, 0);
                }
            }
            #pragma unroll
            for (int lt = 0; lt < 4; ++lt)
                #pragma unroll
                for (int reg = 0; reg < 4; ++reg)
                    s64[lt][reg] += (double)accm[lt][reg];
            __syncthreads();
        }
        const int is_k = (o0 >= 1024);
        const double g  = (double)(is_k ? gamma_k[0] : gamma_q[0]);
        const double be = (double)(is_k ? beta_k[0]  : beta_q[0]);
        const int o_global = osub + m;
        const int o_local  = o_global - (is_k ? 1024 : 0);
        const double bias  = (double)(is_k ? k_b[o_local] : q_b[o_local]);
        float* dest = is_k ? k_s : q_s;
        #pragma unroll
        for (int lt = 0; lt < 4; ++lt) {
            #pragma unroll
            for (int reg = 0; reg < 4; ++reg) {
                double s = (double)corr[lt][0][reg] + (double)corr[lt][1][reg]
                         + s64[lt][reg];
                const int l = lb0 + lt*16 + quad*4 + reg;
                dest[((size_t)(b*LL + l))*OC + o_local] = (float)(g*(s + bias) + be);
            }
        }
    } else {
        const int o0 = (yt - 32) << 6;
        const int osub = o0 + wave*16;
        float4v corr[4];                    // 16 AGPR
        float4v accm[4];                    // 16 AGPR
        double  sv[4][4];
        #pragma unroll
        for (int lt = 0; lt < 4; ++lt) {
            corr[lt] = (float4v){0.f,0.f,0.f,0.f};
            #pragma unroll
            for (int reg = 0; reg < 4; ++reg) sv[lt][reg] = 0.0;
        }
        #pragma unroll
        for (int cidx = 0; cidx < 4; ++cidx) {
            const int cur = cidx & 1;
            if (cidx < 3) {
                const int nc0 = (cidx + 1) << 5;
                for (int e = tid; e < 2*66*4; e += 256) {
                    const int p = e / (66*4), rem = e % (66*4);
                    const int row = rem >> 2, cg = rem & 3;
                    *(bf16x8*)&As[cur ^ 1][p][row][cg*8] =
                        *(const bf16x8*)&xenc[((size_t)(p*2 + b)*XROWS + lb0 + row)*128 + nc0 + cg*8];
                }
            }
            const int c0 = cidx << 5;
            #pragma unroll
            for (int lt = 0; lt < 4; ++lt) accm[lt] = (float4v){0.f,0.f,0.f,0.f};
            size_t base = ((size_t)(osub + m))*128 + c0 + quad*8;
            bf16x8 B1 = *(const bf16x8*)&venc[base];
            bf16x8 B2 = *(const bf16x8*)&venc[base + (size_t)1024*128];
            #pragma unroll
            for (int lt = 0; lt < 4; ++lt) {
                const int row = lt*16 + m + 2;
                bf16x8 A1 = *(const bf16x8*)&As[cur][0][row][quad*8];
                bf16x8 A2 = *(const bf16x8*)&As[cur][1][row][quad*8];
                accm[lt] = __builtin_amdgcn_mfma_f32_16x16x32_bf16(A1, B1, accm[lt], 0, 0, 0);
                corr[lt] = __builtin_amdgcn_mfma_f32_16x16x32_bf16(A1, B2, corr[lt], 0, 0, 0);
                corr[lt] = __builtin_amdgcn_mfma_f32_16x16x32_bf16(A2, B1, corr[lt], 0, 0, 0);
                corr[lt] = __builtin_amdgcn_mfma_f32_16x16x32_bf16(A2, B2, corr[lt], 0, 0, 0);
            }
            #pragma unroll
            for (int lt = 0; lt < 4; ++lt)
                #pragma unroll
                for (int reg = 0; reg < 4; ++reg)
                    sv[lt][reg] += (double)accm[lt][reg];
            __syncthreads();
        }
        const int o_local = osub + m;
        #pragma unroll
        for (int lt = 0; lt < 4; ++lt) {
            #pragma unroll
            for (int reg = 0; reg < 4; ++reg) {
                float s = (float)(sv[lt][reg] + (double)corr[lt][reg]);
                const int l = lb0 + lt*16 + quad*4 + reg;
                v_s[((size_t)(b*LL + l))*OC + o_local] = s;
            }
        }
    }
}

// ---------------------------------------------------------------------------
// Kernel 2: sketch q+k fused, 3-plane/6-pass MFMA in-place; fast_phi epilogue.
// r22: float4 staging loads; r23: vectorized b64 LDS writes (values identical).
// ---------------------------------------------------------------------------
__global__ __launch_bounds__(256) void sketch_mfma_k(
    float* __restrict__ q_s, float* __restrict__ k_s,
    const __bf16* __restrict__ genc_all)
{
    __shared__ __bf16 As[3][32][136];
    const int tid  = threadIdx.x;
    const int wave = tid >> 6;
    const int lane = tid & 63;
    const int m    = lane & 15;
    const int quad = lane >> 4;
    const int half = blockIdx.x >> 10;
    float* buf = half ? k_s : q_s;
    const __bf16* genc = genc_all + (size_t)half*2*3*128*128;
    const size_t i0 = (size_t)(blockIdx.x & 1023) * 32;

    for (int e = tid; e < 32*32; e += 256) {
        const int row = e >> 5, d0 = (e & 31) << 2;
        const float4 v4 = *(const float4*)&buf[(i0 + row)*RR_ + d0];
        const float vs[4] = {v4.x, v4.y, v4.z, v4.w};
        bf16x4 o1, o2, o3;
        #pragma unroll
        for (int j = 0; j < 4; ++j) {
            float v = vs[j];
            __bf16 h1 = (__bf16)v;  float r1 = v - (float)h1;
            __bf16 h2 = (__bf16)r1; float r2 = r1 - (float)h2;
            __bf16 h3 = (__bf16)r2;
            o1[j] = h1; o2[j] = h2; o3[j] = h3;
        }
        *(bf16x4*)&As[0][row][d0] = o1;
        *(bf16x4*)&As[1][row][d0] = o2;
        *(bf16x4*)&As[2][row][d0] = o3;
    }
    __syncthreads();

    float4v accm[2][2][2], corr[2][2][2];
    #pragma unroll
    for (int mt = 0; mt < 2; ++mt)
        #pragma unroll
        for (int nt = 0; nt < 2; ++nt)
            #pragma unroll
            for (int mat = 0; mat < 2; ++mat) {
                accm[mt][nt][mat] = (float4v){0.f,0.f,0.f,0.f};
                corr[mt][nt][mat] = (float4v){0.f,0.f,0.f,0.f};
            }

    #pragma unroll
    for (int ck = 0; ck < 4; ++ck) {
        const int k0 = ck << 5;
        bf16x8 A1[2], A2[2], A3[2];
        #pragma unroll
        for (int mt = 0; mt < 2; ++mt) {
            A1[mt] = *(const bf16x8*)&As[0][mt*16 + m][k0 + quad*8];
            A2[mt] = *(const bf16x8*)&As[1][mt*16 + m][k0 + quad*8];
            A3[mt] = *(const bf16x8*)&As[2][mt*16 + m][k0 + quad*8];
        }
        #pragma unroll
        for (int nt = 0; nt < 2; ++nt) {
            const int r = wave*32 + nt*16 + m;
            #pragma unroll
            for (int mat = 0; mat < 2; ++mat) {
                size_t base = ((size_t)(mat*3)*128 + r)*128 + k0 + quad*8;
                bf16x8 B1 = *(const bf16x8*)&genc[base];
                bf16x8 B2 = *(const bf16x8*)&genc[base + (size_t)128*128];
                bf16x8 B3 = *(const bf16x8*)&genc[base + (size_t)2*128*128];
                #pragma unroll
                for (int mt = 0; mt < 2; ++mt) {
                    accm[mt][nt][mat] = __builtin_amdgcn_mfma_f32_16x16x32_bf16(A1[mt], B1, accm[mt][nt][mat], 0, 0, 0);
                    corr[mt][nt][mat] = __builtin_amdgcn_mfma_f32_16x16x32_bf16(A1[mt], B2, corr[mt][nt][mat], 0, 0, 0);
                    corr[mt][nt][mat] = __builtin_amdgcn_mfma_f32_16x16x32_bf16(A2[mt], B1, corr[mt][nt][mat], 0, 0, 0);
                    corr[mt][nt][mat] = __builtin_amdgcn_mfma_f32_16x16x32_bf16(A1[mt], B3, corr[mt][nt][mat], 0, 0, 0);
                    corr[mt][nt][mat] = __builtin_amdgcn_mfma_f32_16x16x32_bf16(A3[mt], B1, corr[mt][nt][mat], 0, 0, 0);
                    corr[mt][nt][mat] = __builtin_amdgcn_mfma_f32_16x16x32_bf16(A2[mt], B2, corr[mt][nt][mat], 0, 0, 0);
                }
            }
        }
    }
    __syncthreads();

    #pragma unroll
    for (int mt = 0; mt < 2; ++mt)
        #pragma unroll
        for (int nt = 0; nt < 2; ++nt)
            #pragma unroll
            for (int reg = 0; reg < 4; ++reg) {
                double u1 = (double)accm[mt][nt][0][reg] + (double)corr[mt][nt][0][reg];
                double u2 = (double)accm[mt][nt][1][reg] + (double)corr[mt][nt][1][reg];
                const size_t row = i0 + mt*16 + quad*4 + reg;
                const int col = wave*32 + nt*16 + m;
                buf[row*RR_ + col] = fast_phi(u1, u2);
            }
}

// ---------------------------------------------------------------------------
// Kernel 3: KV^T partials via 2-plane MFMA + fp64 Ksum partials (r10-proven).
// Staging left scalar: per-thread ks is keyed to r = tid&127.
// ---------------------------------------------------------------------------
__global__ __launch_bounds__(512) void kv_mfma_k(
    const float* __restrict__ phi_k, const float* __restrict__ v,
    float* __restrict__ part_kv, double* __restrict__ part_ks)
{
    __shared__ float Pt[128*36];
    __shared__ float Vt[128*36];
    __shared__ double ksred[512];
    const int tid  = threadIdx.x;
    const int wave = tid >> 6;
    const int lane = tid & 63;
    const int m    = lane & 15;
    const int quad = lane >> 4;
    const int split = blockIdx.x;
    const int bh    = blockIdx.y;
    const int b = bh >> 3, h = bh & 7;
    const int lbase = split * 128;
    const int dh = wave & 1;
    const int rq = wave >> 1;

    float4v accm[4][2], corr[4][2];
    #pragma unroll
    for (int mt = 0; mt < 4; ++mt)
        #pragma unroll
        for (int nt = 0; nt < 2; ++nt) {
            accm[mt][nt] = (float4v){0.f,0.f,0.f,0.f};
            corr[mt][nt] = (float4v){0.f,0.f,0.f,0.f};
        }
    double ks = 0.0;

    for (int ch = 0; ch < 4; ++ch) {
        __syncthreads();
        for (int e = tid; e < 32*128; e += 512) {
            const int l = e >> 7, r = e & 127;
            size_t base = ((size_t)(b*LL + lbase + ch*32 + l)*HH + h)*RR_;
            float pv = phi_k[base + r];
            float vv = v[base + r];
            Pt[r*36 + l] = pv;
            Vt[r*36 + l] = vv;
            ks += (double)pv;
        }
        __syncthreads();
        bf16x8 A1[4], A2[4], B1[2], B2[2];
        #pragma unroll
        for (int mt = 0; mt < 4; ++mt)
            enc2(&Vt[(dh*64 + mt*16 + m)*36 + quad*8], A1[mt], A2[mt]);
        #pragma unroll
        for (int nt = 0; nt < 2; ++nt)
            enc2(&Pt[(rq*32 + nt*16 + m)*36 + quad*8], B1[nt], B2[nt]);
        #pragma unroll
        for (int mt = 0; mt < 4; ++mt)
            #pragma unroll
            for (int nt = 0; nt < 2; ++nt) {
                accm[mt][nt] = __builtin_amdgcn_mfma_f32_16x16x32_bf16(A1[mt], B1[nt], accm[mt][nt], 0, 0, 0);
                corr[mt][nt] = __builtin_amdgcn_mfma_f32_16x16x32_bf16(A1[mt], B2[nt], corr[mt][nt], 0, 0, 0);
                corr[mt][nt] = __builtin_amdgcn_mfma_f32_16x16x32_bf16(A2[mt], B1[nt], corr[mt][nt], 0, 0, 0);
                corr[mt][nt] = __builtin_amdgcn_mfma_f32_16x16x32_bf16(A2[mt], B2[nt], corr[mt][nt], 0, 0, 0);
            }
    }

    ksred[tid] = ks;
    __syncthreads();
    if (tid < 128) {
        double s = ksred[tid] + ksred[tid+128] + ksred[tid+256] + ksred[tid+384];
        part_ks[(bh*16 + split)*RR_ + tid] = s;
    }

    float* outp = part_kv + ((size_t)(bh*16 + split))*RR_*DD;
    #pragma unroll
    for (int mt = 0; mt < 4; ++mt)
        #pragma unroll
        for (int nt = 0; nt < 2; ++nt)
            #pragma unroll
            for (int reg = 0; reg < 4; ++reg) {
                const int d = dh*64 + mt*16 + quad*4 + reg;
                const int r = rq*32 + nt*16 + m;
                outp[d*128 + r] = accm[mt][nt][reg] + corr[mt][nt][reg];
            }
}

// ---------------------------------------------------------------------------
// Kernel 4: reduce KVT partials -> bf16 2-plane KVTenc.
// ---------------------------------------------------------------------------
__global__ __launch_bounds__(256) void kvreduce_k(
    const float* __restrict__ part_kv, __bf16* __restrict__ kvt_enc)
{
    const int gid = blockIdx.x*256 + threadIdx.x;
    if (gid >= 16*RR_*DD) return;
    const int bh = gid >> 14;
    const int rd = gid & 16383;
    float s = 0.f;
    #pragma unroll
    for (int c = 0; c < 16; ++c)
        s += part_kv[(((size_t)(bh*16 + c)) << 14) + rd];
    __bf16 h1 = (__bf16)s;
    __bf16 h2 = (__bf16)(s - (float)h1);
    kvt_enc[(size_t)bh*16384 + rd] = h1;
    kvt_enc[(size_t)(16 + bh)*16384 + rd] = h2;
}

// ---------------------------------------------------------------------------
// Kernel 5: numerator MFMA + fp64 den (r10-proven). r22: float4 staging.
// ---------------------------------------------------------------------------
__global__ __launch_bounds__(256) void numden_mfma_k(
    const float* __restrict__ phi_q, const __bf16* __restrict__ kvt_enc,
    const double* __restrict__ part_ks, float* __restrict__ o_out)
{
    __shared__ float Pq[64*132];
    __shared__ double Ks_s[128];
    __shared__ double den_s[64];
    const int tid  = threadIdx.x;
    const int wave = tid >> 6;
    const int lane = tid & 63;
    const int m    = lane & 15;
    const int quad = lane >> 4;
    const int lt = blockIdx.x;
    const int bh = blockIdx.y;
    const int b = bh >> 3, h = bh & 7;
    const int l0 = lt * 64;

    if (tid < 128) {
        double s = 0.0;
        #pragma unroll
        for (int c = 0; c < 16; ++c) s += part_ks[(bh*16 + c)*RR_ + tid];
        Ks_s[tid] = s;
    }
    for (int e = tid; e < 64*32; e += 256) {
        const int l = e >> 5, r0 = (e & 31) << 2;
        *(float4*)&Pq[l*132 + r0] =
            *(const float4*)&phi_q[((size_t)(b*LL + l0 + l)*HH + h)*RR_ + r0];
    }
    __syncthreads();

    double den = 0.0;
    if (tid < 64) {
        #pragma unroll
        for (int r = 0; r < 128; ++r)
            den += (double)Pq[tid*132 + r] * Ks_s[r];
    }

    float4v accm[4][2], corr[4][2];
    #pragma unroll
    for (int mt = 0; mt < 4; ++mt)
        #pragma unroll
        for (int nt = 0; nt < 2; ++nt) {
            accm[mt][nt] = (float4v){0.f,0.f,0.f,0.f};
            corr[mt][nt] = (float4v){0.f,0.f,0.f,0.f};
        }

    #pragma unroll
    for (int ck = 0; ck < 4; ++ck) {
        const int k0 = ck << 5;
        bf16x8 A1[4], A2[4];
        #pragma unroll
        for (int mt = 0; mt < 4; ++mt)
            enc2(&Pq[(mt*16 + m)*132 + k0 + quad*8], A1[mt], A2[mt]);
        #pragma unroll
        for (int nt = 0; nt < 2; ++nt) {
            const int d = wave*32 + nt*16 + m;
            size_t base = ((size_t)bh*128 + d)*128 + k0 + quad*8;
            bf16x8 B1 = *(const bf16x8*)&kvt_enc[base];
            bf16x8 B2 = *(const bf16x8*)&kvt_enc[base + (size_t)16*16384];
            #pragma unroll
            for (int mt = 0; mt < 4; ++mt) {
                accm[mt][nt] = __builtin_amdgcn_mfma_f32_16x16x32_bf16(A1[mt], B1, accm[mt][nt], 0, 0, 0);
                corr[mt][nt] = __builtin_amdgcn_mfma_f32_16x16x32_bf16(A1[mt], B2, corr[mt][nt], 0, 0, 0);
                corr[mt][nt] = __builtin_amdgcn_mfma_f32_16x16x32_bf16(A2[mt], B1, corr[mt][nt], 0, 0, 0);
                corr[mt][nt] = __builtin_amdgcn_mfma_f32_16x16x32_bf16(A2[mt], B2, corr[mt][nt], 0, 0, 0);
            }
        }
    }

    __syncthreads();
    if (tid < 64) den_s[tid] = den;
    __syncthreads();

    #pragma unroll
    for (int mt = 0; mt < 4; ++mt)
        #pragma unroll
        for (int nt = 0; nt < 2; ++nt)
            #pragma unroll
            for (int reg = 0; reg < 4; ++reg) {
                const int ll = mt*16 + quad*4 + reg;
                const int d  = wave*32 + nt*16 + m;
                const float inv = (float)(1.0 / (den_s[ll] + 1e-6));
                o_out[((size_t)(b*LL + l0 + ll))*OC + h*DD + d] =
                    (accm[mt][nt][reg] + corr[mt][nt][reg]) * inv;
            }
}

// ---------------------------------------------------------------------------
// Kernel 6: output projection partials via 2-plane MFMA (r10-proven).
// r22: float4 staging.
// ---------------------------------------------------------------------------
__global__ __launch_bounds__(256) void proj_part_mfma_k(
    const float* __restrict__ o_s, const __bf16* __restrict__ penc,
    float* __restrict__ part)
{
    __shared__ float As[32*260];
    const int tid  = threadIdx.x;
    const int wave = tid >> 6;
    const int lane = tid & 63;
    const int m    = lane & 15;
    const int quad = lane >> 4;
    const int row0  = blockIdx.x * 32;
    const int kbase = blockIdx.y * 256;

    for (int e = tid; e < 32*64; e += 256) {
        const int row = e >> 6, k0 = (e & 63) << 2;
        *(float4*)&As[row*260 + k0] =
            *(const float4*)&o_s[(size_t)(row0 + row)*OC + kbase + k0];
    }
    __syncthreads();

    float4v accm[2][2], corr[2][2];
    #pragma unroll
    for (int mt = 0; mt < 2; ++mt)
        #pragma unroll
        for (int nt = 0; nt < 2; ++nt) {
            accm[mt][nt] = (float4v){0.f,0.f,0.f,0.f};
            corr[mt][nt] = (float4v){0.f,0.f,0.f,0.f};
        }

    #pragma unroll
    for (int ck = 0; ck < 8; ++ck) {
        const int k0 = ck << 5;
        bf16x8 A1[2], A2[2];
        #pragma unroll
        for (int mt = 0; mt < 2; ++mt)
            enc2(&As[(mt*16 + m)*260 + k0 + quad*8], A1[mt], A2[mt]);
        #pragma unroll
        for (int nt = 0; nt < 2; ++nt) {
            const int j = wave*32 + nt*16 + m;
            size_t base = ((size_t)j)*OC + kbase + k0 + quad*8;
            bf16x8 B1 = *(const bf16x8*)&penc[base];
            bf16x8 B2 = *(const bf16x8*)&penc[base + (size_t)128*OC];
            #pragma unroll
            for (int mt = 0; mt < 2; ++mt) {
                accm[mt][nt] = __builtin_amdgcn_mfma_f32_16x16x32_bf16(A1[mt], B1, accm[mt][nt], 0, 0, 0);
                corr[mt][nt] = __builtin_amdgcn_mfma_f32_16x16x32_bf16(A1[mt], B2, corr[mt][nt], 0, 0, 0);
                corr[mt][nt] = __builtin_amdgcn_mfma_f32_16x16x32_bf16(A2[mt], B1, corr[mt][nt], 0, 0, 0);
                corr[mt][nt] = __builtin_amdgcn_mfma_f32_16x16x32_bf16(A2[mt], B2, corr[mt][nt], 0, 0, 0);
            }
        }
    }

    float* outp = part + (size_t)blockIdx.y*BL*DD;
    #pragma unroll
    for (int mt = 0; mt < 2; ++mt)
        #pragma unroll
        for (int nt = 0; nt < 2; ++nt)
            #pragma unroll
            for (int reg = 0; reg < 4; ++reg) {
                const int row = row0 + mt*16 + quad*4 + reg;
                const int j   = wave*32 + nt*16 + m;
                outp[(size_t)row*DD + j] = accm[mt][nt][reg] + corr[mt][nt][reg];
            }
}

// ---------------------------------------------------------------------------
// Kernel 7: reduce the 4 K-split partials + bias.
// ---------------------------------------------------------------------------
__global__ __launch_bounds__(256) void proj_reduce_k(
    const float* __restrict__ part, const float* __restrict__ pb,
    float* __restrict__ out)
{
    const int gid = blockIdx.x*256 + threadIdx.x;
    if (gid >= BL*DD/4) return;
    const float4* p4 = (const float4*)part;
    float4 s = p4[gid];
    #pragma unroll
    for (int c = 1; c < 4; ++c) {
        float4 t = p4[gid + (size_t)c*(BL*DD/4)];
        s.x += t.x; s.y += t.y; s.z += t.z; s.w += t.w;
    }
    const int col = (gid << 2) & (DD-1);
    s.x += pb[col]; s.y += pb[col+1]; s.z += pb[col+2]; s.w += pb[col+3];
    ((float4*)out)[gid] = s;
}

// ---------------------------------------------------------------------------
extern "C" void kernel_launch(void* const* d_in, const int* in_sizes, int n_in,
                              void* d_out, int out_size, void* d_ws, size_t ws_size,
                              hipStream_t stream) {
    const float* x       = (const float*)d_in[0];
    const float* q_w     = (const float*)d_in[1];
    const float* q_b     = (const float*)d_in[2];
    const float* k_w     = (const float*)d_in[3];
    const float* k_b     = (const float*)d_in[4];
    const float* v_w     = (const float*)d_in[5];
    const float* g1_q    = (const float*)d_in[6];
    const float* g2_q    = (const float*)d_in[7];
    const float* g1_k    = (const float*)d_in[8];
    const float* g2_k    = (const float*)d_in[9];
    const float* gamma_q = (const float*)d_in[10];
    const float* beta_q  = (const float*)d_in[11];
    const float* gamma_k = (const float*)d_in[12];
    const float* beta_k  = (const float*)d_in[13];
    const float* proj_w  = (const float*)d_in[14];
    const float* proj_b  = (const float*)d_in[15];

    float* f = (float*)d_ws;
    float* q_s     = f;                        // 4,194,304 floats
    float* k_s     = f + 4194304;              // 4,194,304
    float* v_s     = f + 8388608;              // 4,194,304
    float* part_kv = f + 12582912;             // 4,194,304 (scratch: wenc/xenc/kv parts/proj parts)
    double* part_ks = (double*)(f + 16777216); // 32,768 doubles
    __bf16* kvt_enc = (__bf16*)(f + 16842752); // 524,288 bf16
    __bf16* genc   = (__bf16*)(f + 17104896);  // 196,608 bf16
    __bf16* venc   = (__bf16*)(f + 17203200);  // 262,144 bf16
    __bf16* penc   = (__bf16*)(f + 17334272);  // 262,144 bf16
    float* o_s     = k_s;                      // reuse (phi_k dead after kv_mfma)
    float* proj_part = part_kv;                // reuse (kv parts dead after kvreduce)
    __bf16* wenc   = (__bf16*)(f + 12582912);
    __bf16* xenc   = (__bf16*)(f + 13762560);

    dim3 blk(256);
    enc_fused_k<<<2816, blk, 0, stream>>>(q_w, k_w, v_w, proj_w,
                                          g1_q, g2_q, g1_k, g2_k, x,
                                          wenc, genc, venc, penc, xenc);
    conv_mfma_k<<<dim3(64,48), blk, 0, stream>>>(xenc, wenc, venc, q_b, k_b,
                                                 gamma_q, beta_q, gamma_k, beta_k,
                                                 q_s, k_s, v_s);
    sketch_mfma_k<<<2048, blk, 0, stream>>>(q_s, k_s, genc);
    kv_mfma_k<<<dim3(16,16), dim3(512), 0, stream>>>(k_s, v_s, part_kv, part_ks);
    kvreduce_k<<<1024, blk, 0, stream>>>(part_kv, kvt_enc);
    numden_mfma_k<<<dim3(32,16), blk, 0, stream>>>(q_s, kvt_enc, part_ks, o_s);
    proj_part_mfma_k<<<dim3(128,4), blk, 0, stream>>>(o_s, penc, proj_part);
    proj_reduce_k<<<512, blk, 0, stream>>>(proj_part, proj_b, (float*)d_out);
}

// Round 7
// 250.027 us; speedup vs baseline: 1.1522x; 1.0208x over previous
//
#include <hip/hip_runtime.h>
#include <math.h>

// Problem constants
#define BB 2
#define DD 128
#define LL 2048
#define HH 8
#define OC 1024     // H*D
#define RR_ 128
#define BL (BB*LL)          // 4096
#define NROW (BL*HH)        // 32768
#define XROWS 2052

// Numerics ledger (absmax bf16-quantized; threshold 180.48):
//   r3 full fp64 -> 128 PASS | r2 seq fp32 -> 192 FAIL | r5 tanhf -> FAIL
//   r6 chunk4/8+fp64 tanh -> 128 PASS | r7-r11 MFMA ladder -> 64 PASS
//   r14 -> 64 PASS, 268us | r15 4x o-tile -> spill REGRESS | r16 267us
//   r17 B-dbuf neutral | r18 repart+reg-dbuf -> FAIL post-timing divergence
//   r19 repart 32lx32o -> conv 108us REGRESS (B-traffic x2 at fixed occ)
//   r20 lb(256,3): VGPR 80, occ STILL 2 blk -> conv 72.8 (pressure relief)
//   r21 8-wave: occ 41% but conv 96us REGRESS (per-wave MFMA run halved)
//   r22 acc-fold + lb(256,3): VGPR 72, occ still 19.5% -> LDS was the cap.
//   r23 conv chunk-staged dbuf LDS 31,680B -> total 255.2; conv off top-5.
//   Profile now shows sketch_mfma_k ~73us: MfmaUtil 13%, all pipes idle ->
//   latency-bound; inner round is 3 genc loads : 12 MFMA (half conv's ratio).
// r24: sketch mt 2->4 (64-row tiles, 1024 blocks). Round becomes
//      3 loads : 24 MFMA (conv-proven shape). AGPR 64->128, LDS 52,224.
//      Per-output MFMA chain identical (same operands, same ck order)
//      -> bit-identical, absmax 64. Conv and all other kernels = r23.

typedef __bf16  bf16x8  __attribute__((ext_vector_type(8)));
typedef __bf16  bf16x4  __attribute__((ext_vector_type(4)));
typedef float   float4v __attribute__((ext_vector_type(4)));

__device__ __forceinline__ void enc2(const float* src, bf16x8& p1, bf16x8& p2) {
    #pragma unroll
    for (int j = 0; j < 8; ++j) {
        float v = src[j];
        __bf16 h1 = (__bf16)v;
        p1[j] = h1;
        p2[j] = (__bf16)(v - (float)h1);
    }
}

// phi = SR*tanh(u1*u2/SR) = SR*(1 - 2/(2^y + 1)), y = u1*u2*(2/sqrt(128))*log2e.
__device__ __forceinline__ float fast_phi(double u1, double u2) {
    const double TWO_ISR = 0.17677669529663688110;  // 2/sqrt(128) = sqrt(2)/8
    const double LOG2E   = 1.44269504088896340736;  // log2(e)
    const double SR      = 11.313708498984760390;   // sqrt(128)
    double y = (u1*u2) * (TWO_ISR * LOG2E);
    y = fmin(fmax(y, -1020.4), 1020.4);
    double n = rint(y);
    double f = y - n;
    float ff = (float)f;
    float q;
    q = fmaf(1.01780860092396960e-7f, ff, 1.32154867901443094e-6f);
    q = fmaf(q, ff, 1.52527338040598403e-5f);
    q = fmaf(q, ff, 1.54035303933816099e-4f);
    q = fmaf(q, ff, 1.33335581464284434e-3f);
    q = fmaf(q, ff, 9.61812910762847716e-3f);
    q = fmaf(q, ff, 5.55041086648215800e-2f);
    double t2   = fma(f, (double)q, 0.24022650695910071233);
    double head = fma(f, 0.69314718055994530942, 1.0);
    double E0   = fma(f*f, t2, head);
    int ni = (int)n;
    double En = __hiloint2double((ni + 1023) << 20, 0);   // 2^n
    double E  = E0 * En;
    double den = E + 1.0;
    double r = (double)__builtin_amdgcn_rcpf((float)den);
    r = r * fma(-den, r, 2.0);
    r = r * fma(-den, r, 2.0);
    double t = fma(-2.0, r, 1.0);
    return (float)(SR * t);
}

// ---------------------------------------------------------------------------
// Kernel 0: fused encode (weights + x). (r11-proven)
// ---------------------------------------------------------------------------
__global__ __launch_bounds__(256) void enc_fused_k(
    const float* __restrict__ q_w, const float* __restrict__ k_w,
    const float* __restrict__ v_w, const float* __restrict__ pw,
    const float* __restrict__ g1_q, const float* __restrict__ g2_q,
    const float* __restrict__ g1_k, const float* __restrict__ g2_k,
    const float* __restrict__ x,
    __bf16* __restrict__ wenc, __bf16* __restrict__ genc,
    __bf16* __restrict__ venc, __bf16* __restrict__ penc,
    __bf16* __restrict__ xenc)
{
    __shared__ float t[32][33];
    const int bid = blockIdx.x;
    const int tid = threadIdx.x;
    if (bid < 2304) {
        const int gid = bid*256 + tid;
        if (gid < 262144) {
            const int o = gid >> 7, c = gid & 127;
            #pragma unroll
            for (int tt = 0; tt < 3; ++tt) {
                float v = (o < 1024) ? q_w[(o*128 + c)*3 + tt]
                                     : k_w[((o-1024)*128 + c)*3 + tt];
                __bf16 h1 = (__bf16)v;  float r1 = v - (float)h1;
                __bf16 h2 = (__bf16)r1; float r2 = r1 - (float)h2;
                __bf16 h3 = (__bf16)r2;
                wenc[((size_t)(0*3 + tt)*2048 + o)*128 + c] = h1;
                wenc[((size_t)(1*3 + tt)*2048 + o)*128 + c] = h2;
                wenc[((size_t)(2*3 + tt)*2048 + o)*128 + c] = h3;
            }
        } else if (gid < 262144 + 65536) {
            const int g = gid - 262144;
            const int mat = g >> 14, rem = g & 16383;
            const int r = rem >> 7, d = rem & 127;
            const float* src = (mat == 0) ? g1_q : (mat == 1) ? g2_q
                             : (mat == 2) ? g1_k : g2_k;
            float v = src[d*RR_ + r];
            __bf16 h1 = (__bf16)v;  float r1 = v - (float)h1;
            __bf16 h2 = (__bf16)r1; float r2 = r1 - (float)h2;
            __bf16 h3 = (__bf16)r2;
            genc[((size_t)(mat*3 + 0)*128 + r)*128 + d] = h1;
            genc[((size_t)(mat*3 + 1)*128 + r)*128 + d] = h2;
            genc[((size_t)(mat*3 + 2)*128 + r)*128 + d] = h3;
        } else if (gid < 262144 + 65536 + 131072) {
            const int g = gid - 262144 - 65536;
            const int o = g >> 7, c = g & 127;
            float v = v_w[o*128 + c];
            __bf16 h1 = (__bf16)v;  float r1 = v - (float)h1;
            __bf16 h2 = (__bf16)r1;
            venc[((size_t)0*1024 + o)*128 + c] = h1;
            venc[((size_t)1*1024 + o)*128 + c] = h2;
        } else if (gid < 262144 + 65536 + 131072 + 131072) {
            const int g = gid - 262144 - 65536 - 131072;
            const int j = g >> 10, k = g & 1023;
            float v = pw[(size_t)j*OC + k];
            __bf16 h1 = (__bf16)v;  float r1 = v - (float)h1;
            __bf16 h2 = (__bf16)r1;
            penc[((size_t)(0*128 + j))*OC + k] = h1;
            penc[((size_t)(1*128 + j))*OC + k] = h2;
        }
    } else {
        const int g = bid - 2304;
        const int lt = g & 63, ct = (g >> 6) & 3, b = g >> 8;
        const int l0 = lt*32, c0 = ct*32;
        for (int e = tid; e < 32*32; e += 256) {
            int c = e >> 5, l = e & 31;
            t[c][l] = x[((size_t)(b*DD + c0 + c))*LL + l0 + l];
        }
        __syncthreads();
        for (int e = tid; e < 32*32; e += 256) {
            int l = e >> 5, c = e & 31;
            float v = t[c][l];
            __bf16 h1 = (__bf16)v;  float r1 = v - (float)h1;
            __bf16 h2 = (__bf16)r1; float r2 = r1 - (float)h2;
            __bf16 h3 = (__bf16)r2;
            const size_t row = (size_t)(l0 + l + 2);
            xenc[((size_t)(0*2 + b)*XROWS + row)*128 + c0 + c] = h1;
            xenc[((size_t)(1*2 + b)*XROWS + row)*128 + c0 + c] = h2;
            xenc[((size_t)(2*2 + b)*XROWS + row)*128 + c0 + c] = h3;
        }
        if (lt == 0 && ct == 0) {
            for (int e = tid; e < 2*128; e += 256) {
                int row = e >> 7, c = e & 127;
                xenc[((size_t)(0*2 + b)*XROWS + row)*128 + c] = (__bf16)0.f;
                xenc[((size_t)(1*2 + b)*XROWS + row)*128 + c] = (__bf16)0.f;
                xenc[((size_t)(2*2 + b)*XROWS + row)*128 + c] = (__bf16)0.f;
            }
        }
    }
}

// ---------------------------------------------------------------------------
// Kernel 1: fused q+k conv (3-plane/6-pass) AND v (2-plane/4-pass).
// r23: chunk-staged double-buffered LDS. As[2][3][66][40] = 31,680 B.
// ---------------------------------------------------------------------------
__global__ __launch_bounds__(256, 3) void conv_mfma_k(
    const __bf16* __restrict__ xenc, const __bf16* __restrict__ wenc,
    const __bf16* __restrict__ venc,
    const float* __restrict__ q_b, const float* __restrict__ k_b,
    const float* __restrict__ gamma_q, const float* __restrict__ beta_q,
    const float* __restrict__ gamma_k, const float* __restrict__ beta_k,
    float* __restrict__ q_s, float* __restrict__ k_s, float* __restrict__ v_s)
{
    __shared__ __bf16 As[2][3][66][40];
    const int tid  = threadIdx.x;
    const int wave = tid >> 6;
    const int lane = tid & 63;
    const int m    = lane & 15;
    const int quad = lane >> 4;
    const int bx = blockIdx.x;
    const int b  = bx >> 5;
    const int lb0 = (bx & 31) << 6;
    const int yt = blockIdx.y;
    const int is_conv = (yt < 32);
    const int np = is_conv ? 3 : 2;          // v uses planes 0,1 only

    // stage chunk 0 -> buffer 0
    for (int e = tid; e < np*66*4; e += 256) {
        const int p = e / (66*4), rem = e % (66*4);
        const int row = rem >> 2, cg = rem & 3;
        *(bf16x8*)&As[0][p][row][cg*8] =
            *(const bf16x8*)&xenc[((size_t)(p*2 + b)*XROWS + lb0 + row)*128 + cg*8];
    }
    __syncthreads();

    if (is_conv) {
        const int o0 = yt << 6;
        const int osub = o0 + wave*16;
        float4v corr[4][2];                 // 32 AGPR
        float4v accm[4];                    // 16 AGPR (per-chunk)
        double  s64[4][4];                  // fp64 running chunk sums
        #pragma unroll
        for (int lt = 0; lt < 4; ++lt) {
            corr[lt][0] = (float4v){0.f,0.f,0.f,0.f};
            corr[lt][1] = (float4v){0.f,0.f,0.f,0.f};
            #pragma unroll
            for (int reg = 0; reg < 4; ++reg) s64[lt][reg] = 0.0;
        }
        #pragma unroll
        for (int cidx = 0; cidx < 4; ++cidx) {
            const int cur = cidx & 1;
            if (cidx < 3) {
                const int nc0 = (cidx + 1) << 5;
                for (int e = tid; e < 3*66*4; e += 256) {
                    const int p = e / (66*4), rem = e % (66*4);
                    const int row = rem >> 2, cg = rem & 3;
                    *(bf16x8*)&As[cur ^ 1][p][row][cg*8] =
                        *(const bf16x8*)&xenc[((size_t)(p*2 + b)*XROWS + lb0 + row)*128 + nc0 + cg*8];
                }
            }
            const int c0 = cidx << 5;
            #pragma unroll
            for (int lt = 0; lt < 4; ++lt) accm[lt] = (float4v){0.f,0.f,0.f,0.f};
            #pragma unroll
            for (int t = 0; t < 3; ++t) {
                size_t base = ((size_t)t*2048 + osub + m)*128 + c0 + quad*8;
                bf16x8 B1 = *(const bf16x8*)&wenc[base];
                bf16x8 B2 = *(const bf16x8*)&wenc[base + (size_t)3*2048*128];
                bf16x8 B3 = *(const bf16x8*)&wenc[base + (size_t)6*2048*128];
                #pragma unroll
                for (int lt = 0; lt < 4; ++lt) {
                    const int row = lt*16 + m + t;
                    bf16x8 A1 = *(const bf16x8*)&As[cur][0][row][quad*8];
                    bf16x8 A2 = *(const bf16x8*)&As[cur][1][row][quad*8];
                    bf16x8 A3 = *(const bf16x8*)&As[cur][2][row][quad*8];
                    accm[lt]    = __builtin_amdgcn_mfma_f32_16x16x32_bf16(A1, B1, accm[lt], 0, 0, 0);
                    corr[lt][0] = __builtin_amdgcn_mfma_f32_16x16x32_bf16(A1, B2, corr[lt][0], 0, 0, 0);
                    corr[lt][1] = __builtin_amdgcn_mfma_f32_16x16x32_bf16(A2, B1, corr[lt][1], 0, 0, 0);
                    corr[lt][0] = __builtin_amdgcn_mfma_f32_16x16x32_bf16(A1, B3, corr[lt][0], 0, 0, 0);
                    corr[lt][1] = __builtin_amdgcn_mfma_f32_16x16x32_bf16(A3, B1, corr[lt][1], 0, 0, 0);
                    corr[lt][0] = __builtin_amdgcn_mfma_f32_16x16x32_bf16(A2, B2, corr[lt][0], 0, 0, 0);
                }
            }
            #pragma unroll
            for (int lt = 0; lt < 4; ++lt)
                #pragma unroll
                for (int reg = 0; reg < 4; ++reg)
                    s64[lt][reg] += (double)accm[lt][reg];
            __syncthreads();
        }
        const int is_k = (o0 >= 1024);
        const double g  = (double)(is_k ? gamma_k[0] : gamma_q[0]);
        const double be = (double)(is_k ? beta_k[0]  : beta_q[0]);
        const int o_global = osub + m;
        const int o_local  = o_global - (is_k ? 1024 : 0);
        const double bias  = (double)(is_k ? k_b[o_local] : q_b[o_local]);
        float* dest = is_k ? k_s : q_s;
        #pragma unroll
        for (int lt = 0; lt < 4; ++lt) {
            #pragma unroll
            for (int reg = 0; reg < 4; ++reg) {
                double s = (double)corr[lt][0][reg] + (double)corr[lt][1][reg]
                         + s64[lt][reg];
                const int l = lb0 + lt*16 + quad*4 + reg;
                dest[((size_t)(b*LL + l))*OC + o_local] = (float)(g*(s + bias) + be);
            }
        }
    } else {
        const int o0 = (yt - 32) << 6;
        const int osub = o0 + wave*16;
        float4v corr[4];                    // 16 AGPR
        float4v accm[4];                    // 16 AGPR
        double  sv[4][4];
        #pragma unroll
        for (int lt = 0; lt < 4; ++lt) {
            corr[lt] = (float4v){0.f,0.f,0.f,0.f};
            #pragma unroll
            for (int reg = 0; reg < 4; ++reg) sv[lt][reg] = 0.0;
        }
        #pragma unroll
        for (int cidx = 0; cidx < 4; ++cidx) {
            const int cur = cidx & 1;
            if (cidx < 3) {
                const int nc0 = (cidx + 1) << 5;
                for (int e = tid; e < 2*66*4; e += 256) {
                    const int p = e / (66*4), rem = e % (66*4);
                    const int row = rem >> 2, cg = rem & 3;
                    *(bf16x8*)&As[cur ^ 1][p][row][cg*8] =
                        *(const bf16x8*)&xenc[((size_t)(p*2 + b)*XROWS + lb0 + row)*128 + nc0 + cg*8];
                }
            }
            const int c0 = cidx << 5;
            #pragma unroll
            for (int lt = 0; lt < 4; ++lt) accm[lt] = (float4v){0.f,0.f,0.f,0.f};
            size_t base = ((size_t)(osub + m))*128 + c0 + quad*8;
            bf16x8 B1 = *(const bf16x8*)&venc[base];
            bf16x8 B2 = *(const bf16x8*)&venc[base + (size_t)1024*128];
            #pragma unroll
            for (int lt = 0; lt < 4; ++lt) {
                const int row = lt*16 + m + 2;
                bf16x8 A1 = *(const bf16x8*)&As[cur][0][row][quad*8];
                bf16x8 A2 = *(const bf16x8*)&As[cur][1][row][quad*8];
                accm[lt] = __builtin_amdgcn_mfma_f32_16x16x32_bf16(A1, B1, accm[lt], 0, 0, 0);
                corr[lt] = __builtin_amdgcn_mfma_f32_16x16x32_bf16(A1, B2, corr[lt], 0, 0, 0);
                corr[lt] = __builtin_amdgcn_mfma_f32_16x16x32_bf16(A2, B1, corr[lt], 0, 0, 0);
                corr[lt] = __builtin_amdgcn_mfma_f32_16x16x32_bf16(A2, B2, corr[lt], 0, 0, 0);
            }
            #pragma unroll
            for (int lt = 0; lt < 4; ++lt)
                #pragma unroll
                for (int reg = 0; reg < 4; ++reg)
                    sv[lt][reg] += (double)accm[lt][reg];
            __syncthreads();
        }
        const int o_local = osub + m;
        #pragma unroll
        for (int lt = 0; lt < 4; ++lt) {
            #pragma unroll
            for (int reg = 0; reg < 4; ++reg) {
                float s = (float)(sv[lt][reg] + (double)corr[lt][reg]);
                const int l = lb0 + lt*16 + quad*4 + reg;
                v_s[((size_t)(b*LL + l))*OC + o_local] = s;
            }
        }
    }
}

// ---------------------------------------------------------------------------
// Kernel 2: sketch q+k fused, 3-plane/6-pass MFMA in-place; fast_phi epilogue.
// r24: mt=4 (64-row tiles), 1024 blocks (512/half). Per (ck,nt,mat) round:
// 3 genc loads feed 24 MFMAs (conv-proven intensity; was 12). Per-output
// MFMA chain identical to r22/r23 -> bit-identical, absmax 64.
// LDS As[3][64][136] = 52,224 B; AGPR 128.
// ---------------------------------------------------------------------------
__global__ __launch_bounds__(256) void sketch_mfma_k(
    float* __restrict__ q_s, float* __restrict__ k_s,
    const __bf16* __restrict__ genc_all)
{
    __shared__ __bf16 As[3][64][136];
    const int tid  = threadIdx.x;
    const int wave = tid >> 6;
    const int lane = tid & 63;
    const int m    = lane & 15;
    const int quad = lane >> 4;
    const int half = blockIdx.x >> 9;
    float* buf = half ? k_s : q_s;
    const __bf16* genc = genc_all + (size_t)half*2*3*128*128;
    const size_t i0 = (size_t)(blockIdx.x & 511) * 64;

    for (int e = tid; e < 64*32; e += 256) {
        const int row = e >> 5, d0 = (e & 31) << 2;
        const float4 v4 = *(const float4*)&buf[(i0 + row)*RR_ + d0];
        const float vs[4] = {v4.x, v4.y, v4.z, v4.w};
        bf16x4 o1, o2, o3;
        #pragma unroll
        for (int j = 0; j < 4; ++j) {
            float v = vs[j];
            __bf16 h1 = (__bf16)v;  float r1 = v - (float)h1;
            __bf16 h2 = (__bf16)r1; float r2 = r1 - (float)h2;
            __bf16 h3 = (__bf16)r2;
            o1[j] = h1; o2[j] = h2; o3[j] = h3;
        }
        *(bf16x4*)&As[0][row][d0] = o1;
        *(bf16x4*)&As[1][row][d0] = o2;
        *(bf16x4*)&As[2][row][d0] = o3;
    }
    __syncthreads();

    float4v accm[4][2][2], corr[4][2][2];
    #pragma unroll
    for (int mt = 0; mt < 4; ++mt)
        #pragma unroll
        for (int nt = 0; nt < 2; ++nt)
            #pragma unroll
            for (int mat = 0; mat < 2; ++mat) {
                accm[mt][nt][mat] = (float4v){0.f,0.f,0.f,0.f};
                corr[mt][nt][mat] = (float4v){0.f,0.f,0.f,0.f};
            }

    #pragma unroll
    for (int ck = 0; ck < 4; ++ck) {
        const int k0 = ck << 5;
        bf16x8 A1[4], A2[4], A3[4];
        #pragma unroll
        for (int mt = 0; mt < 4; ++mt) {
            A1[mt] = *(const bf16x8*)&As[0][mt*16 + m][k0 + quad*8];
            A2[mt] = *(const bf16x8*)&As[1][mt*16 + m][k0 + quad*8];
            A3[mt] = *(const bf16x8*)&As[2][mt*16 + m][k0 + quad*8];
        }
        #pragma unroll
        for (int nt = 0; nt < 2; ++nt) {
            const int r = wave*32 + nt*16 + m;
            #pragma unroll
            for (int mat = 0; mat < 2; ++mat) {
                size_t base = ((size_t)(mat*3)*128 + r)*128 + k0 + quad*8;
                bf16x8 B1 = *(const bf16x8*)&genc[base];
                bf16x8 B2 = *(const bf16x8*)&genc[base + (size_t)128*128];
                bf16x8 B3 = *(const bf16x8*)&genc[base + (size_t)2*128*128];
                #pragma unroll
                for (int mt = 0; mt < 4; ++mt) {
                    accm[mt][nt][mat] = __builtin_amdgcn_mfma_f32_16x16x32_bf16(A1[mt], B1, accm[mt][nt][mat], 0, 0, 0);
                    corr[mt][nt][mat] = __builtin_amdgcn_mfma_f32_16x16x32_bf16(A1[mt], B2, corr[mt][nt][mat], 0, 0, 0);
                    corr[mt][nt][mat] = __builtin_amdgcn_mfma_f32_16x16x32_bf16(A2[mt], B1, corr[mt][nt][mat], 0, 0, 0);
                    corr[mt][nt][mat] = __builtin_amdgcn_mfma_f32_16x16x32_bf16(A1[mt], B3, corr[mt][nt][mat], 0, 0, 0);
                    corr[mt][nt][mat] = __builtin_amdgcn_mfma_f32_16x16x32_bf16(A3[mt], B1, corr[mt][nt][mat], 0, 0, 0);
                    corr[mt][nt][mat] = __builtin_amdgcn_mfma_f32_16x16x32_bf16(A2[mt], B2, corr[mt][nt][mat], 0, 0, 0);
                }
            }
        }
    }
    __syncthreads();

    #pragma unroll
    for (int mt = 0; mt < 4; ++mt)
        #pragma unroll
        for (int nt = 0; nt < 2; ++nt)
            #pragma unroll
            for (int reg = 0; reg < 4; ++reg) {
                double u1 = (double)accm[mt][nt][0][reg] + (double)corr[mt][nt][0][reg];
                double u2 = (double)accm[mt][nt][1][reg] + (double)corr[mt][nt][1][reg];
                const size_t row = i0 + mt*16 + quad*4 + reg;
                const int col = wave*32 + nt*16 + m;
                buf[row*RR_ + col] = fast_phi(u1, u2);
            }
}

// ---------------------------------------------------------------------------
// Kernel 3: KV^T partials via 2-plane MFMA + fp64 Ksum partials (r10-proven).
// Staging left scalar: per-thread ks is keyed to r = tid&127.
// ---------------------------------------------------------------------------
__global__ __launch_bounds__(512) void kv_mfma_k(
    const float* __restrict__ phi_k, const float* __restrict__ v,
    float* __restrict__ part_kv, double* __restrict__ part_ks)
{
    __shared__ float Pt[128*36];
    __shared__ float Vt[128*36];
    __shared__ double ksred[512];
    const int tid  = threadIdx.x;
    const int wave = tid >> 6;
    const int lane = tid & 63;
    const int m    = lane & 15;
    const int quad = lane >> 4;
    const int split = blockIdx.x;
    const int bh    = blockIdx.y;
    const int b = bh >> 3, h = bh & 7;
    const int lbase = split * 128;
    const int dh = wave & 1;
    const int rq = wave >> 1;

    float4v accm[4][2], corr[4][2];
    #pragma unroll
    for (int mt = 0; mt < 4; ++mt)
        #pragma unroll
        for (int nt = 0; nt < 2; ++nt) {
            accm[mt][nt] = (float4v){0.f,0.f,0.f,0.f};
            corr[mt][nt] = (float4v){0.f,0.f,0.f,0.f};
        }
    double ks = 0.0;

    for (int ch = 0; ch < 4; ++ch) {
        __syncthreads();
        for (int e = tid; e < 32*128; e += 512) {
            const int l = e >> 7, r = e & 127;
            size_t base = ((size_t)(b*LL + lbase + ch*32 + l)*HH + h)*RR_;
            float pv = phi_k[base + r];
            float vv = v[base + r];
            Pt[r*36 + l] = pv;
            Vt[r*36 + l] = vv;
            ks += (double)pv;
        }
        __syncthreads();
        bf16x8 A1[4], A2[4], B1[2], B2[2];
        #pragma unroll
        for (int mt = 0; mt < 4; ++mt)
            enc2(&Vt[(dh*64 + mt*16 + m)*36 + quad*8], A1[mt], A2[mt]);
        #pragma unroll
        for (int nt = 0; nt < 2; ++nt)
            enc2(&Pt[(rq*32 + nt*16 + m)*36 + quad*8], B1[nt], B2[nt]);
        #pragma unroll
        for (int mt = 0; mt < 4; ++mt)
            #pragma unroll
            for (int nt = 0; nt < 2; ++nt) {
                accm[mt][nt] = __builtin_amdgcn_mfma_f32_16x16x32_bf16(A1[mt], B1[nt], accm[mt][nt], 0, 0, 0);
                corr[mt][nt] = __builtin_amdgcn_mfma_f32_16x16x32_bf16(A1[mt], B2[nt], corr[mt][nt], 0, 0, 0);
                corr[mt][nt] = __builtin_amdgcn_mfma_f32_16x16x32_bf16(A2[mt], B1[nt], corr[mt][nt], 0, 0, 0);
                corr[mt][nt] = __builtin_amdgcn_mfma_f32_16x16x32_bf16(A2[mt], B2[nt], corr[mt][nt], 0, 0, 0);
            }
    }

    ksred[tid] = ks;
    __syncthreads();
    if (tid < 128) {
        double s = ksred[tid] + ksred[tid+128] + ksred[tid+256] + ksred[tid+384];
        part_ks[(bh*16 + split)*RR_ + tid] = s;
    }

    float* outp = part_kv + ((size_t)(bh*16 + split))*RR_*DD;
    #pragma unroll
    for (int mt = 0; mt < 4; ++mt)
        #pragma unroll
        for (int nt = 0; nt < 2; ++nt)
            #pragma unroll
            for (int reg = 0; reg < 4; ++reg) {
                const int d = dh*64 + mt*16 + quad*4 + reg;
                const int r = rq*32 + nt*16 + m;
                outp[d*128 + r] = accm[mt][nt][reg] + corr[mt][nt][reg];
            }
}

// ---------------------------------------------------------------------------
// Kernel 4: reduce KVT partials -> bf16 2-plane KVTenc.
// ---------------------------------------------------------------------------
__global__ __launch_bounds__(256) void kvreduce_k(
    const float* __restrict__ part_kv, __bf16* __restrict__ kvt_enc)
{
    const int gid = blockIdx.x*256 + threadIdx.x;
    if (gid >= 16*RR_*DD) return;
    const int bh = gid >> 14;
    const int rd = gid & 16383;
    float s = 0.f;
    #pragma unroll
    for (int c = 0; c < 16; ++c)
        s += part_kv[(((size_t)(bh*16 + c)) << 14) + rd];
    __bf16 h1 = (__bf16)s;
    __bf16 h2 = (__bf16)(s - (float)h1);
    kvt_enc[(size_t)bh*16384 + rd] = h1;
    kvt_enc[(size_t)(16 + bh)*16384 + rd] = h2;
}

// ---------------------------------------------------------------------------
// Kernel 5: numerator MFMA + fp64 den (r10-proven). r22: float4 staging.
// ---------------------------------------------------------------------------
__global__ __launch_bounds__(256) void numden_mfma_k(
    const float* __restrict__ phi_q, const __bf16* __restrict__ kvt_enc,
    const double* __restrict__ part_ks, float* __restrict__ o_out)
{
    __shared__ float Pq[64*132];
    __shared__ double Ks_s[128];
    __shared__ double den_s[64];
    const int tid  = threadIdx.x;
    const int wave = tid >> 6;
    const int lane = tid & 63;
    const int m    = lane & 15;
    const int quad = lane >> 4;
    const int lt = blockIdx.x;
    const int bh = blockIdx.y;
    const int b = bh >> 3, h = bh & 7;
    const int l0 = lt * 64;

    if (tid < 128) {
        double s = 0.0;
        #pragma unroll
        for (int c = 0; c < 16; ++c) s += part_ks[(bh*16 + c)*RR_ + tid];
        Ks_s[tid] = s;
    }
    for (int e = tid; e < 64*32; e += 256) {
        const int l = e >> 5, r0 = (e & 31) << 2;
        *(float4*)&Pq[l*132 + r0] =
            *(const float4*)&phi_q[((size_t)(b*LL + l0 + l)*HH + h)*RR_ + r0];
    }
    __syncthreads();

    double den = 0.0;
    if (tid < 64) {
        #pragma unroll
        for (int r = 0; r < 128; ++r)
            den += (double)Pq[tid*132 + r] * Ks_s[r];
    }

    float4v accm[4][2], corr[4][2];
    #pragma unroll
    for (int mt = 0; mt < 4; ++mt)
        #pragma unroll
        for (int nt = 0; nt < 2; ++nt) {
            accm[mt][nt] = (float4v){0.f,0.f,0.f,0.f};
            corr[mt][nt] = (float4v){0.f,0.f,0.f,0.f};
        }

    #pragma unroll
    for (int ck = 0; ck < 4; ++ck) {
        const int k0 = ck << 5;
        bf16x8 A1[4], A2[4];
        #pragma unroll
        for (int mt = 0; mt < 4; ++mt)
            enc2(&Pq[(mt*16 + m)*132 + k0 + quad*8], A1[mt], A2[mt]);
        #pragma unroll
        for (int nt = 0; nt < 2; ++nt) {
            const int d = wave*32 + nt*16 + m;
            size_t base = ((size_t)bh*128 + d)*128 + k0 + quad*8;
            bf16x8 B1 = *(const bf16x8*)&kvt_enc[base];
            bf16x8 B2 = *(const bf16x8*)&kvt_enc[base + (size_t)16*16384];
            #pragma unroll
            for (int mt = 0; mt < 4; ++mt) {
                accm[mt][nt] = __builtin_amdgcn_mfma_f32_16x16x32_bf16(A1[mt], B1, accm[mt][nt], 0, 0, 0);
                corr[mt][nt] = __builtin_amdgcn_mfma_f32_16x16x32_bf16(A1[mt], B2, corr[mt][nt], 0, 0, 0);
                corr[mt][nt] = __builtin_amdgcn_mfma_f32_16x16x32_bf16(A2[mt], B1, corr[mt][nt], 0, 0, 0);
                corr[mt][nt] = __builtin_amdgcn_mfma_f32_16x16x32_bf16(A2[mt], B2, corr[mt][nt], 0, 0, 0);
            }
        }
    }

    __syncthreads();
    if (tid < 64) den_s[tid] = den;
    __syncthreads();

    #pragma unroll
    for (int mt = 0; mt < 4; ++mt)
        #pragma unroll
        for (int nt = 0; nt < 2; ++nt)
            #pragma unroll
            for (int reg = 0; reg < 4; ++reg) {
                const int ll = mt*16 + quad*4 + reg;
                const int d  = wave*32 + nt*16 + m;
                const float inv = (float)(1.0 / (den_s[ll] + 1e-6));
                o_out[((size_t)(b*LL + l0 + ll))*OC + h*DD + d] =
                    (accm[mt][nt][reg] + corr[mt][nt][reg]) * inv;
            }
}

// ---------------------------------------------------------------------------
// Kernel 6: output projection partials via 2-plane MFMA (r10-proven).
// r22: float4 staging.
// ---------------------------------------------------------------------------
__global__ __launch_bounds__(256) void proj_part_mfma_k(
    const float* __restrict__ o_s, const __bf16* __restrict__ penc,
    float* __restrict__ part)
{
    __shared__ float As[32*260];
    const int tid  = threadIdx.x;
    const int wave = tid >> 6;
    const int lane = tid & 63;
    const int m    = lane & 15;
    const int quad = lane >> 4;
    const int row0  = blockIdx.x * 32;
    const int kbase = blockIdx.y * 256;

    for (int e = tid; e < 32*64; e += 256) {
        const int row = e >> 6, k0 = (e & 63) << 2;
        *(float4*)&As[row*260 + k0] =
            *(const float4*)&o_s[(size_t)(row0 + row)*OC + kbase + k0];
    }
    __syncthreads();

    float4v accm[2][2], corr[2][2];
    #pragma unroll
    for (int mt = 0; mt < 2; ++mt)
        #pragma unroll
        for (int nt = 0; nt < 2; ++nt) {
            accm[mt][nt] = (float4v){0.f,0.f,0.f,0.f};
            corr[mt][nt] = (float4v){0.f,0.f,0.f,0.f};
        }

    #pragma unroll
    for (int ck = 0; ck < 8; ++ck) {
        const int k0 = ck << 5;
        bf16x8 A1[2], A2[2];
        #pragma unroll
        for (int mt = 0; mt < 2; ++mt)
            enc2(&As[(mt*16 + m)*260 + k0 + quad*8], A1[mt], A2[mt]);
        #pragma unroll
        for (int nt = 0; nt < 2; ++nt) {
            const int j = wave*32 + nt*16 + m;
            size_t base = ((size_t)j)*OC + kbase + k0 + quad*8;
            bf16x8 B1 = *(const bf16x8*)&penc[base];
            bf16x8 B2 = *(const bf16x8*)&penc[base + (size_t)128*OC];
            #pragma unroll
            for (int mt = 0; mt < 2; ++mt) {
                accm[mt][nt] = __builtin_amdgcn_mfma_f32_16x16x32_bf16(A1[mt], B1, accm[mt][nt], 0, 0, 0);
                corr[mt][nt] = __builtin_amdgcn_mfma_f32_16x16x32_bf16(A1[mt], B2, corr[mt][nt], 0, 0, 0);
                corr[mt][nt] = __builtin_amdgcn_mfma_f32_16x16x32_bf16(A2[mt], B1, corr[mt][nt], 0, 0, 0);
                corr[mt][nt] = __builtin_amdgcn_mfma_f32_16x16x32_bf16(A2[mt], B2, corr[mt][nt], 0, 0, 0);
            }
        }
    }

    float* outp = part + (size_t)blockIdx.y*BL*DD;
    #pragma unroll
    for (int mt = 0; mt < 2; ++mt)
        #pragma unroll
        for (int nt = 0; nt < 2; ++nt)
            #pragma unroll
            for (int reg = 0; reg < 4; ++reg) {
                const int row = row0 + mt*16 + quad*4 + reg;
                const int j   = wave*32 + nt*16 + m;
                outp[(size_t)row*DD + j] = accm[mt][nt][reg] + corr[mt][nt][reg];
            }
}

// ---------------------------------------------------------------------------
// Kernel 7: reduce the 4 K-split partials + bias.
// ---------------------------------------------------------------------------
__global__ __launch_bounds__(256) void proj_reduce_k(
    const float* __restrict__ part, const float* __restrict__ pb,
    float* __restrict__ out)
{
    const int gid = blockIdx.x*256 + threadIdx.x;
    if (gid >= BL*DD/4) return;
    const float4* p4 = (const float4*)part;
    float4 s = p4[gid];
    #pragma unroll
    for (int c = 1; c < 4; ++c) {
        float4 t = p4[gid + (size_t)c*(BL*DD/4)];
        s.x += t.x; s.y += t.y; s.z += t.z; s.w += t.w;
    }
    const int col = (gid << 2) & (DD-1);
    s.x += pb[col]; s.y += pb[col+1]; s.z += pb[col+2]; s.w += pb[col+3];
    ((float4*)out)[gid] = s;
}

// ---------------------------------------------------------------------------
extern "C" void kernel_launch(void* const* d_in, const int* in_sizes, int n_in,
                              void* d_out, int out_size, void* d_ws, size_t ws_size,
                              hipStream_t stream) {
    const float* x       = (const float*)d_in[0];
    const float* q_w     = (const float*)d_in[1];
    const float* q_b     = (const float*)d_in[2];
    const float* k_w     = (const float*)d_in[3];
    const float* k_b     = (const float*)d_in[4];
    const float* v_w     = (const float*)d_in[5];
    const float* g1_q    = (const float*)d_in[6];
    const float* g2_q    = (const float*)d_in[7];
    const float* g1_k    = (const float*)d_in[8];
    const float* g2_k    = (const float*)d_in[9];
    const float* gamma_q = (const float*)d_in[10];
    const float* beta_q  = (const float*)d_in[11];
    const float* gamma_k = (const float*)d_in[12];
    const float* beta_k  = (const float*)d_in[13];
    const float* proj_w  = (const float*)d_in[14];
    const float* proj_b  = (const float*)d_in[15];

    float* f = (float*)d_ws;
    float* q_s     = f;                        // 4,194,304 floats
    float* k_s     = f + 4194304;              // 4,194,304
    float* v_s     = f + 8388608;              // 4,194,304
    float* part_kv = f + 12582912;             // 4,194,304 (scratch: wenc/xenc/kv parts/proj parts)
    double* part_ks = (double*)(f + 16777216); // 32,768 doubles
    __bf16* kvt_enc = (__bf16*)(f + 16842752); // 524,288 bf16
    __bf16* genc   = (__bf16*)(f + 17104896);  // 196,608 bf16
    __bf16* venc   = (__bf16*)(f + 17203200);  // 262,144 bf16
    __bf16* penc   = (__bf16*)(f + 17334272);  // 262,144 bf16
    float* o_s     = k_s;                      // reuse (phi_k dead after kv_mfma)
    float* proj_part = part_kv;                // reuse (kv parts dead after kvreduce)
    __bf16* wenc   = (__bf16*)(f + 12582912);
    __bf16* xenc   = (__bf16*)(f + 13762560);

    dim3 blk(256);
    enc_fused_k<<<2816, blk, 0, stream>>>(q_w, k_w, v_w, proj_w,
                                          g1_q, g2_q, g1_k, g2_k, x,
                                          wenc, genc, venc, penc, xenc);
    conv_mfma_k<<<dim3(64,48), blk, 0, stream>>>(xenc, wenc, venc, q_b, k_b,
                                                 gamma_q, beta_q, gamma_k, beta_k,
                                                 q_s, k_s, v_s);
    sketch_mfma_k<<<1024, blk, 0, stream>>>(q_s, k_s, genc);
    kv_mfma_k<<<dim3(16,16), dim3(512), 0, stream>>>(k_s, v_s, part_kv, part_ks);
    kvreduce_k<<<1024, blk, 0, stream>>>(part_kv, kvt_enc);
    numden_mfma_k<<<dim3(32,16), blk, 0, stream>>>(q_s, kvt_enc, part_ks, o_s);
    proj_part_mfma_k<<<dim3(128,4), blk, 0, stream>>>(o_s, penc, proj_part);
    proj_reduce_k<<<512, blk, 0, stream>>>(proj_part, proj_b, (float*)d_out);
}